// Round 6
// baseline (248.425 us; speedup 1.0000x reference)
//
#include <hip/hip_runtime.h>
#include <hip/hip_bf16.h>
#include <math.h>

// Problem constants
#define NB 2
#define CC 256
#define NPOS 2304   // 48*48
#define NDELTA 95

typedef __attribute__((ext_vector_type(8))) short short8;
typedef __attribute__((ext_vector_type(4))) float floatx4;

__device__ inline unsigned short f2bf(float x) {
    unsigned int u = __float_as_uint(x);
    u = (u + 0x7FFFu + ((u >> 16) & 1u)) >> 16;
    return (unsigned short)u;
}
__device__ inline float bf2f(unsigned short h) {
    return __uint_as_float(((unsigned int)h) << 16);
}
__device__ inline unsigned int pk2(float a, float b) {
    return (unsigned int)f2bf(a) | ((unsigned int)f2bf(b) << 16);
}
__device__ inline unsigned int pkmul(unsigned int a, unsigned int b) {
    __hip_bfloat162 x = *(__hip_bfloat162*)&a;
    __hip_bfloat162 y = *(__hip_bfloat162*)&b;
    __hip_bfloat162 r = __hmul2(x, y);
    return *(unsigned int*)&r;
}

// ---------------------------------------------------------------------------
// Kernel 1: pos tables (posx/posy: [95][256]) + wk_eff ([8][256])
// ---------------------------------------------------------------------------
__global__ __launch_bounds__(256) void pos_tables_kernel(
    const float* __restrict__ Wx, const float* __restrict__ Wy,
    const float* __restrict__ Wk, const float* __restrict__ ab,
    float* __restrict__ posx, float* __restrict__ posy, float* __restrict__ wkeff)
{
    int b = blockIdx.x;
    int t = threadIdx.x;
    if (b < NDELTA) {
        __shared__ float emb[128];
        float delta = (float)(b - 47);
        if (t < 64) {
            float dim_inv = exp2f(-(float)t * 0.15571537944784511f); // log2(1000)/64
            float ang = 2.0f * delta * dim_inv;
            emb[t]      = sinf(ang);
            emb[t + 64] = cosf(ang);
        }
        __syncthreads();
        float sx = 0.f, sy = 0.f;
        const float* wxr = Wx + t * 128;
        const float* wyr = Wy + t * 128;
        for (int f = 0; f < 128; ++f) {
            float e = emb[f];
            sx += e * wxr[f];
            sy += e * wyr[f];
        }
        const float inv_sqrt2 = 0.70710678118654752440f;
        posx[b * 256 + t] = sx * inv_sqrt2;
        posy[b * 256 + t] = sy * inv_sqrt2;
    } else {
        int g = b - NDELTA;
        float s = 0.f;
        for (int d = 0; d < 32; ++d)
            s += ab[g * 32 + d] * Wk[(g * 32 + d) * 256 + t];
        wkeff[g * 256 + t] = s;
    }
}

// ---------------------------------------------------------------------------
// Kernel 1b: extract strided x into contiguous xs[n][c][48*48]
// ---------------------------------------------------------------------------
__global__ __launch_bounds__(256) void extract_kernel(
    const float* __restrict__ x, float* __restrict__ xs)
{
    int idx = blockIdx.x * 256 + threadIdx.x;   // 294912 threads, 4 elems each
    int f = idx * 4;
    int nc = f / NPOS;
    int rem = f - nc * NPOS;
    int i = rem / 48, j = rem - i * 48;         // j multiple of 4, stays in row
    const float* row = x + (size_t)nc * (96 * 96) + (2 * i) * 96 + 2 * j;
    *(float4*)(xs + f) = make_float4(row[0], row[2], row[4], row[6]);
}

// ---------------------------------------------------------------------------
// Kernel 2: fused Q/V/e_key projection GEMM (B = contiguous xs).
// qbuf layout: [ng][p][32d]   vbuf layout: [n][256ch][p]   ek: [ng][p]
// ---------------------------------------------------------------------------
__global__ __launch_bounds__(256) void qkv_kernel(
    const float* __restrict__ xs, const float* __restrict__ Wq,
    const float* __restrict__ Wv, const float* __restrict__ wkeff,
    float* __restrict__ qbuf, float* __restrict__ vbuf, float* __restrict__ ek)
{
    __shared__ float As[16][64];
    __shared__ float Bs[16][64];
    int mTile = blockIdx.x;   // 0..8
    int nTile = blockIdx.y;   // 0..71
    int t = threadIdx.x;
    int tx = t & 15, ty = t >> 4;
    int colBase = nTile * 64;
    int n = colBase / NPOS;
    int pBase = colBase - n * NPOS;

    int lo = t & 63;
    int lc = (t >> 6) * 4;
    int bc = t >> 4;
    int bp = (t & 15) * 4;

    float acc[4][4] = {};

    for (int k0 = 0; k0 < 256; k0 += 16) {
        int o = mTile * 64 + lo;
        float4 w4 = make_float4(0.f, 0.f, 0.f, 0.f);
        if (o < 256)      w4 = *(const float4*)(Wq + o * 256 + k0 + lc);
        else if (o < 512) w4 = *(const float4*)(Wv + (o - 256) * 256 + k0 + lc);
        else if (o < 520) w4 = *(const float4*)(wkeff + (o - 512) * 256 + k0 + lc);
        As[lc + 0][lo] = w4.x;
        As[lc + 1][lo] = w4.y;
        As[lc + 2][lo] = w4.z;
        As[lc + 3][lo] = w4.w;

        int c = k0 + bc;
        *(float4*)&Bs[bc][bp] =
            *(const float4*)(xs + ((size_t)(n * 256 + c)) * NPOS + pBase + bp);
        __syncthreads();

        #pragma unroll
        for (int kk = 0; kk < 16; ++kk) {
            float4 av = *(const float4*)&As[kk][ty * 4];
            float4 b4 = *(const float4*)&Bs[kk][tx * 4];
            float a[4] = {av.x, av.y, av.z, av.w};
            float bb[4] = {b4.x, b4.y, b4.z, b4.w};
            #pragma unroll
            for (int i = 0; i < 4; ++i)
                #pragma unroll
                for (int j = 0; j < 4; ++j)
                    acc[i][j] += a[i] * bb[j];
        }
        __syncthreads();
    }

    #pragma unroll
    for (int i = 0; i < 4; ++i) {
        int o = mTile * 64 + ty * 4 + i;
        if (o >= 520) continue;
        int p0 = pBase + tx * 4;
        if (o < 256) {
            int g = o >> 5, d = o & 31;
            #pragma unroll
            for (int j = 0; j < 4; ++j)
                qbuf[((size_t)(n * 8 + g) * NPOS + p0 + j) * 32 + d] = acc[i][j];
        } else if (o < 512) {
            int o2 = o - 256;
            *(float4*)(vbuf + (size_t)(n * 256 + o2) * NPOS + p0) =
                make_float4(acc[i][0], acc[i][1], acc[i][2], acc[i][3]);
        } else {
            *(float4*)(ek + (size_t)(n * 8 + (o - 512)) * NPOS + p0) =
                make_float4(acc[i][0], acc[i][1], acc[i][2], acc[i][3]);
        }
    }
}

// ---------------------------------------------------------------------------
// Kernel 3: per-(n,g) A = exp(ek - max(ek)), in place.
// ---------------------------------------------------------------------------
__global__ __launch_bounds__(256) void softA_kernel(float* __restrict__ ekA)
{
    int ng = blockIdx.x;
    float* e = ekA + (size_t)ng * NPOS;
    int t = threadIdx.x;
    __shared__ float red[256];
    float m = -1e30f;
    for (int k = t; k < NPOS; k += 256) m = fmaxf(m, e[k]);
    red[t] = m;
    __syncthreads();
    for (int s = 128; s > 0; s >>= 1) {
        if (t < s) red[t] = fmaxf(red[t], red[t + s]);
        __syncthreads();
    }
    m = red[0];
    for (int k = t; k < NPOS; k += 256) e[k] = __expf(e[k] - m);
}

// ---------------------------------------------------------------------------
// Kernel 3b: V̂ = A*V in bf16 B-fragment order, once per (n,g).
// ---------------------------------------------------------------------------
__global__ __launch_bounds__(256) void vhat_kernel(
    const float* __restrict__ vbuf, const float* __restrict__ ekA,
    uint4* __restrict__ vhat)
{
    int tile = blockIdx.x;   // 0..23
    int ng = blockIdx.y;     // 0..15
    int k0 = tile * 96;
    int t = threadIdx.x;
    const float* vb = vbuf + (size_t)ng * 32 * NPOS;   // [32 d][2304 k]
    const float* Ab = ekA + (size_t)ng * NPOS;
    uint4* out = vhat + ((size_t)ng * 24 + tile) * 576;

    for (int s = t; s < 576; s += 256) {
        int grp = s >> 6;
        int Ls = s & 63;
        int cc = grp / 3;
        int nn = grp - cc * 3;
        int koct = cc * 32 + ((Ls >> 4) << 3);
        uint4 w = make_uint4(0u, 0u, 0u, 0u);
        if (nn < 2) {
            int d = nn * 16 + (Ls & 15);
            const float* vp = vb + (size_t)d * NPOS + k0 + koct;
            const float* ap = Ab + k0 + koct;
            float4 v0 = *(const float4*)vp;
            float4 v1 = *(const float4*)(vp + 4);
            float4 a0 = *(const float4*)ap;
            float4 a1 = *(const float4*)(ap + 4);
            w.x = pk2(v0.x * a0.x, v0.y * a0.y);
            w.y = pk2(v0.z * a0.z, v0.w * a0.w);
            w.z = pk2(v1.x * a1.x, v1.y * a1.y);
            w.w = pk2(v1.z * a1.z, v1.w * a1.w);
        } else if ((Ls & 15) == 0) {
            const float* ap = Ab + k0 + koct;
            float4 a0 = *(const float4*)ap;
            float4 a1 = *(const float4*)(ap + 4);
            w.x = pk2(a0.x, a0.y);
            w.y = pk2(a0.z, a0.w);
            w.z = pk2(a1.x, a1.y);
            w.w = pk2(a1.z, a1.w);
        }
        out[s] = w;
    }
}

// ---------------------------------------------------------------------------
// Kernel 4: attention via bf16 MFMA. Barrier-free k-loop.
// __launch_bounds__(256, 2): 2 waves/EU floor -> 256-VGPR budget -> NO
// scratch spills (r5's VGPR_Count=48 spilled Qr[32]+b[9] and cost ~75 us).
// Grid is 2.25 blocks/CU anyway, so the occupancy cap costs nothing.
// ---------------------------------------------------------------------------
__global__ __launch_bounds__(256, 2) void attn_kernel(
    const float* __restrict__ qbuf, const uint4* __restrict__ vhat,
    const float* __restrict__ posx, const float* __restrict__ posy,
    float* __restrict__ oattn)
{
    __shared__ unsigned short Xs[64 * 50];   // 6400 B
    __shared__ unsigned short Ys[64 * 50];   // 6400 B
    __shared__ float linv_s[64];

    int blk = blockIdx.x;
    int qt = blk % 36;
    int ng = blk / 36;
    int nb = ng >> 3, g = ng & 7;
    int qbase = qt * 64;
    int t = threadIdx.x;
    int m = t >> 6;     // wave id = q-group
    int L = t & 63;

    // ---- e_x / e_y phase: X = exp(q·posx), Y = exp(q·posy) (no shift) ----
    {
        int qlo = L >> 3, rlo = L & 7;
        for (int pass = 0; pass < 2; ++pass) {
            int oct = pass * 4 + m;           // q-octet 0..7
            int q = oct * 8 + qlo;
            int qglob = qbase + q;
            int base8 = qbase + oct * 8;
            int hq0 = base8 / 48;
            int sq0 = base8 - hq0 * 48;       // no wrap within octet
            int wq = sq0 + qlo;
            float Qr[32];
            const float* qsrc = qbuf + ((size_t)ng * NPOS + qglob) * 32;
            #pragma unroll
            for (int j = 0; j < 8; ++j) {
                float4 qv = *(const float4*)(qsrc + j * 4);
                Qr[j * 4 + 0] = qv.x; Qr[j * 4 + 1] = qv.y;
                Qr[j * 4 + 2] = qv.z; Qr[j * 4 + 3] = qv.w;
            }
            #pragma unroll
            for (int rb = 0; rb < 7; ++rb) {
                int row = sq0 + rb * 8 + rlo;
                if (row < 95) {
                    const float* px = posx + (size_t)row * 256 + g * 32;
                    float s = 0.f;
                    #pragma unroll
                    for (int ch = 0; ch < 8; ++ch) {
                        float4 pv = *(const float4*)(px + ch * 4);
                        s += pv.x * Qr[ch*4+0] + pv.y * Qr[ch*4+1]
                           + pv.z * Qr[ch*4+2] + pv.w * Qr[ch*4+3];
                    }
                    int v = wq - row + 47;
                    if (v >= 0 && v < 48)
                        Xs[q * 50 + v] = f2bf(__expf(s));
                }
            }
            #pragma unroll
            for (int rb = 0; rb < 7; ++rb) {
                int row = hq0 + rb * 8 + rlo;
                if (row < 95) {
                    const float* py = posy + (size_t)row * 256 + g * 32;
                    float s = 0.f;
                    #pragma unroll
                    for (int ch = 0; ch < 8; ++ch) {
                        float4 pv = *(const float4*)(py + ch * 4);
                        s += pv.x * Qr[ch*4+0] + pv.y * Qr[ch*4+1]
                           + pv.z * Qr[ch*4+2] + pv.w * Qr[ch*4+3];
                    }
                    int u = hq0 - row + 47;
                    if (u >= 0 && u < 48)
                        Ys[q * 50 + u] = f2bf(__expf(s));
                }
            }
        }
    }
    __syncthreads();

    // ---- preload packed X pairs ----
    int qp = m * 16 + (L & 15);
    int o = L >> 4;
    unsigned int Xp[12];
    #pragma unroll
    for (int c = 0; c < 3; ++c)
        #pragma unroll
        for (int jj = 0; jj < 4; ++jj) {
            int k = c * 32 + o * 8 + jj * 2;       // even; pair never straddles 48
            int v0 = (k < 48) ? k : k - 48;
            int v1 = v0 + 1;
            Xp[c * 4 + jj] = (unsigned int)Xs[qp * 50 + v0]
                           | ((unsigned int)Xs[qp * 50 + v1] << 16);
        }

    floatx4 acc0 = {0.f, 0.f, 0.f, 0.f};
    floatx4 acc1 = {0.f, 0.f, 0.f, 0.f};
    floatx4 acc2 = {0.f, 0.f, 0.f, 0.f};

    const uint4* vb = vhat + (size_t)ng * 24 * 576 + L;

    for (int tile = 0; tile < 24; ++tile) {
        const uint4* src = vb + tile * 576;
        uint4 b[9];
        #pragma unroll
        for (int gix = 0; gix < 9; ++gix)
            b[gix] = src[gix * 64];

        int u0 = tile * 2;
        unsigned int y0 = Ys[qp * 50 + u0];     y0 |= y0 << 16;
        unsigned int y1 = Ys[qp * 50 + u0 + 1]; y1 |= y1 << 16;
        unsigned int Yc[3];
        Yc[0] = y0; Yc[1] = (o < 2) ? y0 : y1; Yc[2] = y1;

        #pragma unroll
        for (int c = 0; c < 3; ++c) {
            unsigned int yv = Yc[c];
            union { unsigned int u[4]; short8 s; } av;
            av.u[0] = pkmul(Xp[c * 4 + 0], yv);
            av.u[1] = pkmul(Xp[c * 4 + 1], yv);
            av.u[2] = pkmul(Xp[c * 4 + 2], yv);
            av.u[3] = pkmul(Xp[c * 4 + 3], yv);
            short8 a = av.s;
            acc0 = __builtin_amdgcn_mfma_f32_16x16x32_bf16(
                a, *(const short8*)&b[c * 3 + 0], acc0, 0, 0, 0);
            acc1 = __builtin_amdgcn_mfma_f32_16x16x32_bf16(
                a, *(const short8*)&b[c * 3 + 1], acc1, 0, 0, 0);
            acc2 = __builtin_amdgcn_mfma_f32_16x16x32_bf16(
                a, *(const short8*)&b[c * 3 + 2], acc2, 0, 0, 0);
        }
    }

    // ---- epilogue: l from acc2 col 0, normalize, store ----
    if ((L & 15) == 0) {
        int qc = m * 16 + (L >> 4) * 4;
        #pragma unroll
        for (int r = 0; r < 4; ++r)
            linv_s[qc + r] = 1.0f / acc2[r];
    }
    __syncthreads();
    {
        int qc = m * 16 + (L >> 4) * 4;
        float4 li = *(const float4*)&linv_s[qc];
        int d0 = L & 15;
        float* r0 = oattn + ((size_t)(nb * 256 + g * 32 + d0)) * NPOS + qbase + qc;
        *(float4*)r0 = make_float4(acc0[0] * li.x, acc0[1] * li.y,
                                   acc0[2] * li.z, acc0[3] * li.w);
        float* r1 = oattn + ((size_t)(nb * 256 + g * 32 + 16 + d0)) * NPOS + qbase + qc;
        *(float4*)r1 = make_float4(acc1[0] * li.x, acc1[1] * li.y,
                                   acc1[2] * li.z, acc1[3] * li.w);
    }
}

// ---------------------------------------------------------------------------
// Kernel 5: output projection GEMM
// ---------------------------------------------------------------------------
__global__ __launch_bounds__(256) void proj_kernel(
    const float* __restrict__ oattn, const float* __restrict__ Wp,
    const float* __restrict__ bpv, float* __restrict__ proj)
{
    __shared__ float As[16][64];
    __shared__ float Bs[16][64];
    int mTile = blockIdx.x;   // 0..3
    int nTile = blockIdx.y;   // 0..71
    int t = threadIdx.x;
    int tx = t & 15, ty = t >> 4;
    int colBase = nTile * 64;
    int n = colBase / NPOS;
    int pBase = colBase - n * NPOS;

    int lo = t & 63;
    int lc = (t >> 6) * 4;
    int bc = t >> 4;
    int bp = (t & 15) * 4;

    float acc[4][4] = {};

    for (int k0 = 0; k0 < 256; k0 += 16) {
        int o = mTile * 64 + lo;
        float4 w4 = *(const float4*)(Wp + o * 256 + k0 + lc);
        As[lc + 0][lo] = w4.x;
        As[lc + 1][lo] = w4.y;
        As[lc + 2][lo] = w4.z;
        As[lc + 3][lo] = w4.w;
        int c = k0 + bc;
        *(float4*)&Bs[bc][bp] =
            *(const float4*)(oattn + ((size_t)(n * 256 + c)) * NPOS + pBase + bp);
        __syncthreads();
        #pragma unroll
        for (int kk = 0; kk < 16; ++kk) {
            float4 av = *(const float4*)&As[kk][ty * 4];
            float4 b4 = *(const float4*)&Bs[kk][tx * 4];
            float a[4] = {av.x, av.y, av.z, av.w};
            float bb[4] = {b4.x, b4.y, b4.z, b4.w};
            #pragma unroll
            for (int i = 0; i < 4; ++i)
                #pragma unroll
                for (int j = 0; j < 4; ++j)
                    acc[i][j] += a[i] * bb[j];
        }
        __syncthreads();
    }

    #pragma unroll
    for (int i = 0; i < 4; ++i) {
        int o = mTile * 64 + ty * 4 + i;
        float bias = bpv[o];
        *(float4*)(proj + ((size_t)(n * 256 + o)) * NPOS + pBase + tx * 4) =
            make_float4(acc[i][0] + bias, acc[i][1] + bias,
                        acc[i][2] + bias, acc[i][3] + bias);
    }
}

// ---------------------------------------------------------------------------
// Kernel 6: bilinear 48->96 upsample + residual
// ---------------------------------------------------------------------------
__global__ __launch_bounds__(256) void resize_kernel(
    const float* __restrict__ proj, const float* __restrict__ x,
    const float* __restrict__ gamma, float* __restrict__ out)
{
    int idx = blockIdx.x * 256 + threadIdx.x;
    int J = idx % 96;
    int tmp = idx / 96;
    int I = tmp % 96;
    int nc = tmp / 96;

    int jr = I >> 1;
    int r0, r1; float w0, w1;
    if ((I & 1) == 0) { r0 = (jr > 0) ? jr - 1 : 0; r1 = jr; w0 = 0.25f; w1 = 0.75f; }
    else              { r0 = jr; r1 = (jr < 47) ? jr + 1 : 47; w0 = 0.75f; w1 = 0.25f; }
    int jc = J >> 1;
    int c0, c1; float u0, u1;
    if ((J & 1) == 0) { c0 = (jc > 0) ? jc - 1 : 0; c1 = jc; u0 = 0.25f; u1 = 0.75f; }
    else              { c0 = jc; c1 = (jc < 47) ? jc + 1 : 47; u0 = 0.75f; u1 = 0.25f; }

    const float* P = proj + (size_t)nc * NPOS;
    float v = w0 * (u0 * P[r0 * 48 + c0] + u1 * P[r0 * 48 + c1]) +
              w1 * (u0 * P[r1 * 48 + c0] + u1 * P[r1 * 48 + c1]);
    out[idx] = gamma[0] * v + x[idx];
}

// ---------------------------------------------------------------------------
extern "C" void kernel_launch(void* const* d_in, const int* in_sizes, int n_in,
                              void* d_out, int out_size, void* d_ws, size_t ws_size,
                              hipStream_t stream)
{
    const float* x     = (const float*)d_in[0];
    const float* Wq    = (const float*)d_in[1];
    const float* Wk    = (const float*)d_in[2];
    const float* Wv    = (const float*)d_in[3];
    const float* Wx    = (const float*)d_in[4];
    const float* Wy    = (const float*)d_in[5];
    const float* ab    = (const float*)d_in[6];
    const float* Wp    = (const float*)d_in[7];
    const float* bp    = (const float*)d_in[8];
    const float* gamma = (const float*)d_in[9];
    float* out = (float*)d_out;

    float* ws = (float*)d_ws;
    float* posx  = ws;                               // 95*256
    float* posy  = posx + 95 * 256;                  // 95*256
    float* wkeff = posy + 95 * 256;                  // 8*256
    float* qbuf  = wkeff + 8 * 256;                  // 2*8*2304*32  [ng][p][32]
    float* vbuf  = qbuf + 2 * 8 * NPOS * 32;         // 2*8*2304*32  [n][256][p]
    float* ekA   = vbuf + 2 * 8 * NPOS * 32;         // 2*8*2304
    float* oattn = ekA + 2 * 8 * NPOS;               // 2*256*2304
    float* proj  = oattn + 2 * 256 * NPOS;           // 2*256*2304
    // Aliases (stream-ordered lifetimes):
    //   xs (extract output, dead after qkv) aliases oattn (written by attn later)
    //   vhat (dead after attn) aliases proj (written by proj_kernel later)
    float* xs    = oattn;                            // 2*256*2304
    uint4* vhat  = (uint4*)proj;                     // 16*24*576 uint4 (3.54 MB)

    hipLaunchKernelGGL(pos_tables_kernel, dim3(103), dim3(256), 0, stream,
                       Wx, Wy, Wk, ab, posx, posy, wkeff);
    hipLaunchKernelGGL(extract_kernel, dim3(1152), dim3(256), 0, stream, x, xs);
    hipLaunchKernelGGL(qkv_kernel, dim3(9, 72), dim3(256), 0, stream,
                       xs, Wq, Wv, wkeff, qbuf, vbuf, ekA);
    hipLaunchKernelGGL(softA_kernel, dim3(16), dim3(256), 0, stream, ekA);
    hipLaunchKernelGGL(vhat_kernel, dim3(24, 16), dim3(256), 0, stream,
                       vbuf, ekA, vhat);
    hipLaunchKernelGGL(attn_kernel, dim3(576), dim3(256), 0, stream,
                       qbuf, vhat, posx, posy, oattn);
    hipLaunchKernelGGL(proj_kernel, dim3(4, 72), dim3(256), 0, stream,
                       oattn, Wp, bp, proj);
    hipLaunchKernelGGL(resize_kernel, dim3((2 * 256 * 96 * 96) / 256), dim3(256), 0, stream,
                       proj, x, gamma, out);
}

// Round 7
// 240.014 us; speedup vs baseline: 1.0350x; 1.0350x over previous
//
#include <hip/hip_runtime.h>
#include <hip/hip_bf16.h>
#include <math.h>

// Problem constants
#define NB 2
#define CC 256
#define NPOS 2304   // 48*48
#define NDELTA 95

typedef __attribute__((ext_vector_type(8))) short short8;
typedef __attribute__((ext_vector_type(4))) float floatx4;

__device__ inline unsigned short f2bf(float x) {
    unsigned int u = __float_as_uint(x);
    u = (u + 0x7FFFu + ((u >> 16) & 1u)) >> 16;
    return (unsigned short)u;
}
__device__ inline unsigned int pk2(float a, float b) {
    return (unsigned int)f2bf(a) | ((unsigned int)f2bf(b) << 16);
}
__device__ inline unsigned int pkmul(unsigned int a, unsigned int b) {
    __hip_bfloat162 x = *(__hip_bfloat162*)&a;
    __hip_bfloat162 y = *(__hip_bfloat162*)&b;
    __hip_bfloat162 r = __hmul2(x, y);
    return *(unsigned int*)&r;
}

// ---------------------------------------------------------------------------
// Kernel 1: pos tables (posx/posy: [95][256]) + wk_eff ([8][256])
// ---------------------------------------------------------------------------
__global__ __launch_bounds__(256) void pos_tables_kernel(
    const float* __restrict__ Wx, const float* __restrict__ Wy,
    const float* __restrict__ Wk, const float* __restrict__ ab,
    float* __restrict__ posx, float* __restrict__ posy, float* __restrict__ wkeff)
{
    int b = blockIdx.x;
    int t = threadIdx.x;
    if (b < NDELTA) {
        __shared__ float emb[128];
        float delta = (float)(b - 47);
        if (t < 64) {
            float dim_inv = exp2f(-(float)t * 0.15571537944784511f); // log2(1000)/64
            float ang = 2.0f * delta * dim_inv;
            emb[t]      = sinf(ang);
            emb[t + 64] = cosf(ang);
        }
        __syncthreads();
        float sx = 0.f, sy = 0.f;
        const float* wxr = Wx + t * 128;
        const float* wyr = Wy + t * 128;
        for (int f = 0; f < 128; ++f) {
            float e = emb[f];
            sx += e * wxr[f];
            sy += e * wyr[f];
        }
        const float inv_sqrt2 = 0.70710678118654752440f;
        posx[b * 256 + t] = sx * inv_sqrt2;
        posy[b * 256 + t] = sy * inv_sqrt2;
    } else {
        int g = b - NDELTA;
        float s = 0.f;
        for (int d = 0; d < 32; ++d)
            s += ab[g * 32 + d] * Wk[(g * 32 + d) * 256 + t];
        wkeff[g * 256 + t] = s;
    }
}

// ---------------------------------------------------------------------------
// Kernel 1b: extract strided x into contiguous xs[n][c][48*48]
// ---------------------------------------------------------------------------
__global__ __launch_bounds__(256) void extract_kernel(
    const float* __restrict__ x, float* __restrict__ xs)
{
    int idx = blockIdx.x * 256 + threadIdx.x;
    int f = idx * 4;
    int nc = f / NPOS;
    int rem = f - nc * NPOS;
    int i = rem / 48, j = rem - i * 48;
    const float* row = x + (size_t)nc * (96 * 96) + (2 * i) * 96 + 2 * j;
    *(float4*)(xs + f) = make_float4(row[0], row[2], row[4], row[6]);
}

// ---------------------------------------------------------------------------
// Kernel 2: fused Q/V/e_key projection GEMM (B = contiguous xs).
// ---------------------------------------------------------------------------
__global__ __launch_bounds__(256) void qkv_kernel(
    const float* __restrict__ xs, const float* __restrict__ Wq,
    const float* __restrict__ Wv, const float* __restrict__ wkeff,
    float* __restrict__ qbuf, float* __restrict__ vbuf, float* __restrict__ ek)
{
    __shared__ float As[16][64];
    __shared__ float Bs[16][64];
    int mTile = blockIdx.x;   // 0..8
    int nTile = blockIdx.y;   // 0..71
    int t = threadIdx.x;
    int tx = t & 15, ty = t >> 4;
    int colBase = nTile * 64;
    int n = colBase / NPOS;
    int pBase = colBase - n * NPOS;

    int lo = t & 63;
    int lc = (t >> 6) * 4;
    int bc = t >> 4;
    int bp = (t & 15) * 4;

    float acc[4][4] = {};

    for (int k0 = 0; k0 < 256; k0 += 16) {
        int o = mTile * 64 + lo;
        float4 w4 = make_float4(0.f, 0.f, 0.f, 0.f);
        if (o < 256)      w4 = *(const float4*)(Wq + o * 256 + k0 + lc);
        else if (o < 512) w4 = *(const float4*)(Wv + (o - 256) * 256 + k0 + lc);
        else if (o < 520) w4 = *(const float4*)(wkeff + (o - 512) * 256 + k0 + lc);
        As[lc + 0][lo] = w4.x;
        As[lc + 1][lo] = w4.y;
        As[lc + 2][lo] = w4.z;
        As[lc + 3][lo] = w4.w;

        int c = k0 + bc;
        *(float4*)&Bs[bc][bp] =
            *(const float4*)(xs + ((size_t)(n * 256 + c)) * NPOS + pBase + bp);
        __syncthreads();

        #pragma unroll
        for (int kk = 0; kk < 16; ++kk) {
            float4 av = *(const float4*)&As[kk][ty * 4];
            float4 b4 = *(const float4*)&Bs[kk][tx * 4];
            float a[4] = {av.x, av.y, av.z, av.w};
            float bb[4] = {b4.x, b4.y, b4.z, b4.w};
            #pragma unroll
            for (int i = 0; i < 4; ++i)
                #pragma unroll
                for (int j = 0; j < 4; ++j)
                    acc[i][j] += a[i] * bb[j];
        }
        __syncthreads();
    }

    #pragma unroll
    for (int i = 0; i < 4; ++i) {
        int o = mTile * 64 + ty * 4 + i;
        if (o >= 520) continue;
        int p0 = pBase + tx * 4;
        if (o < 256) {
            int g = o >> 5, d = o & 31;
            #pragma unroll
            for (int j = 0; j < 4; ++j)
                qbuf[((size_t)(n * 8 + g) * NPOS + p0 + j) * 32 + d] = acc[i][j];
        } else if (o < 512) {
            int o2 = o - 256;
            *(float4*)(vbuf + (size_t)(n * 256 + o2) * NPOS + p0) =
                make_float4(acc[i][0], acc[i][1], acc[i][2], acc[i][3]);
        } else {
            *(float4*)(ek + (size_t)(n * 8 + (o - 512)) * NPOS + p0) =
                make_float4(acc[i][0], acc[i][1], acc[i][2], acc[i][3]);
        }
    }
}

// ---------------------------------------------------------------------------
// Kernel 3: per-(n,g) A = exp(ek - max(ek)), in place.
// ---------------------------------------------------------------------------
__global__ __launch_bounds__(256) void softA_kernel(float* __restrict__ ekA)
{
    int ng = blockIdx.x;
    float* e = ekA + (size_t)ng * NPOS;
    int t = threadIdx.x;
    __shared__ float red[256];
    float m = -1e30f;
    for (int k = t; k < NPOS; k += 256) m = fmaxf(m, e[k]);
    red[t] = m;
    __syncthreads();
    for (int s = 128; s > 0; s >>= 1) {
        if (t < s) red[t] = fmaxf(red[t], red[t + s]);
        __syncthreads();
    }
    m = red[0];
    for (int k = t; k < NPOS; k += 256) e[k] = __expf(e[k] - m);
}

// ---------------------------------------------------------------------------
// Kernel 3b: V̂ = A*V in bf16 B-fragment order, once per (n,g).
// ---------------------------------------------------------------------------
__global__ __launch_bounds__(256) void vhat_kernel(
    const float* __restrict__ vbuf, const float* __restrict__ ekA,
    uint4* __restrict__ vhat)
{
    int tile = blockIdx.x;   // 0..23
    int ng = blockIdx.y;     // 0..15
    int k0 = tile * 96;
    int t = threadIdx.x;
    const float* vb = vbuf + (size_t)ng * 32 * NPOS;
    const float* Ab = ekA + (size_t)ng * NPOS;
    uint4* out = vhat + ((size_t)ng * 24 + tile) * 576;

    for (int s = t; s < 576; s += 256) {
        int grp = s >> 6;
        int Ls = s & 63;
        int cc = grp / 3;
        int nn = grp - cc * 3;
        int koct = cc * 32 + ((Ls >> 4) << 3);
        uint4 w = make_uint4(0u, 0u, 0u, 0u);
        if (nn < 2) {
            int d = nn * 16 + (Ls & 15);
            const float* vp = vb + (size_t)d * NPOS + k0 + koct;
            const float* ap = Ab + k0 + koct;
            float4 v0 = *(const float4*)vp;
            float4 v1 = *(const float4*)(vp + 4);
            float4 a0 = *(const float4*)ap;
            float4 a1 = *(const float4*)(ap + 4);
            w.x = pk2(v0.x * a0.x, v0.y * a0.y);
            w.y = pk2(v0.z * a0.z, v0.w * a0.w);
            w.z = pk2(v1.x * a1.x, v1.y * a1.y);
            w.w = pk2(v1.z * a1.z, v1.w * a1.w);
        } else if ((Ls & 15) == 0) {
            const float* ap = Ab + k0 + koct;
            float4 a0 = *(const float4*)ap;
            float4 a1 = *(const float4*)(ap + 4);
            w.x = pk2(a0.x, a0.y);
            w.y = pk2(a0.z, a0.w);
            w.z = pk2(a1.x, a1.y);
            w.w = pk2(a1.z, a1.w);
        }
        out[s] = w;
    }
}

// ---------------------------------------------------------------------------
// Kernel 3c: exy — X/Y exp tables. xtab[ng][q][48], ytab[ng][q][48] (bf16).
// Thread = (query, 1/8 of outputs): 6 X-dots + 6 Y-dots of length 32,
// each with 4 split accumulators (8-deep chains) for ILP.
// ---------------------------------------------------------------------------
__global__ __launch_bounds__(256, 2) void exy_kernel(
    const float* __restrict__ qbuf, const float* __restrict__ posx,
    const float* __restrict__ posy, unsigned short* __restrict__ xtab,
    unsigned short* __restrict__ ytab)
{
    int blk = blockIdx.x;          // 16*72
    int chunk = blk % 72;
    int ng = blk / 72;
    int g = ng & 7;
    int t = threadIdx.x;
    int qi = t >> 3;               // 0..31
    int part = t & 7;              // 0..7
    int qglob = chunk * 32 + qi;
    int hq = qglob / 48;
    int wq = qglob - hq * 48;

    float Qr[32];
    const float* qsrc = qbuf + ((size_t)ng * NPOS + qglob) * 32;
    #pragma unroll
    for (int j = 0; j < 8; ++j) {
        float4 qv = *(const float4*)(qsrc + j * 4);
        Qr[j * 4 + 0] = qv.x; Qr[j * 4 + 1] = qv.y;
        Qr[j * 4 + 2] = qv.z; Qr[j * 4 + 3] = qv.w;
    }

    unsigned int xo[3], yo[3];
    #pragma unroll
    for (int dp = 0; dp < 3; ++dp) {
        unsigned short rx[2], ry[2];
        #pragma unroll
        for (int dd = 0; dd < 2; ++dd) {
            int v = part * 6 + dp * 2 + dd;
            const float* px = posx + (size_t)(wq + 47 - v) * 256 + g * 32;
            const float* py = posy + (size_t)(hq + 47 - v) * 256 + g * 32;
            float sx0 = 0.f, sx1 = 0.f, sx2 = 0.f, sx3 = 0.f;
            float sy0 = 0.f, sy1 = 0.f, sy2 = 0.f, sy3 = 0.f;
            #pragma unroll
            for (int ch = 0; ch < 8; ++ch) {
                float4 pv = *(const float4*)(px + ch * 4);
                float4 pw = *(const float4*)(py + ch * 4);
                sx0 += pv.x * Qr[ch * 4 + 0];
                sx1 += pv.y * Qr[ch * 4 + 1];
                sx2 += pv.z * Qr[ch * 4 + 2];
                sx3 += pv.w * Qr[ch * 4 + 3];
                sy0 += pw.x * Qr[ch * 4 + 0];
                sy1 += pw.y * Qr[ch * 4 + 1];
                sy2 += pw.z * Qr[ch * 4 + 2];
                sy3 += pw.w * Qr[ch * 4 + 3];
            }
            rx[dd] = f2bf(__expf((sx0 + sx1) + (sx2 + sx3)));
            ry[dd] = f2bf(__expf((sy0 + sy1) + (sy2 + sy3)));
        }
        xo[dp] = (unsigned int)rx[0] | ((unsigned int)rx[1] << 16);
        yo[dp] = (unsigned int)ry[0] | ((unsigned int)ry[1] << 16);
    }
    size_t base = ((size_t)ng * NPOS + qglob) * 48 + part * 6;  // *2B -> 4-aligned
    unsigned int* xd = (unsigned int*)(xtab + base);
    unsigned int* yd = (unsigned int*)(ytab + base);
    xd[0] = xo[0]; xd[1] = xo[1]; xd[2] = xo[2];
    yd[0] = yo[0]; yd[1] = yo[1]; yd[2] = yo[2];
}

// ---------------------------------------------------------------------------
// Kernel 4: attention, pure MFMA k-loop. Unroll-by-2 register prefetch:
// tile t+1's 9 B-fragments load while tile t's MFMAs run.
// ---------------------------------------------------------------------------
#define DO_TILE(BB, TT) do {                                                   \
    int u0_ = (TT) * 2;                                                        \
    unsigned int y0_ = YsL[qp * 50 + u0_];     y0_ |= y0_ << 16;               \
    unsigned int y1_ = YsL[qp * 50 + u0_ + 1]; y1_ |= y1_ << 16;               \
    unsigned int Yc0_ = y0_, Yc1_ = (o < 2) ? y0_ : y1_, Yc2_ = y1_;           \
    union { unsigned int u[4]; short8 s; } av_;                                \
    av_.u[0] = pkmul(Xp[0], Yc0_); av_.u[1] = pkmul(Xp[1], Yc0_);              \
    av_.u[2] = pkmul(Xp[2], Yc0_); av_.u[3] = pkmul(Xp[3], Yc0_);              \
    acc0 = __builtin_amdgcn_mfma_f32_16x16x32_bf16(av_.s, *(const short8*)&BB[0], acc0, 0, 0, 0); \
    acc1 = __builtin_amdgcn_mfma_f32_16x16x32_bf16(av_.s, *(const short8*)&BB[1], acc1, 0, 0, 0); \
    acc2 = __builtin_amdgcn_mfma_f32_16x16x32_bf16(av_.s, *(const short8*)&BB[2], acc2, 0, 0, 0); \
    av_.u[0] = pkmul(Xp[4], Yc1_); av_.u[1] = pkmul(Xp[5], Yc1_);              \
    av_.u[2] = pkmul(Xp[6], Yc1_); av_.u[3] = pkmul(Xp[7], Yc1_);              \
    acc0 = __builtin_amdgcn_mfma_f32_16x16x32_bf16(av_.s, *(const short8*)&BB[3], acc0, 0, 0, 0); \
    acc1 = __builtin_amdgcn_mfma_f32_16x16x32_bf16(av_.s, *(const short8*)&BB[4], acc1, 0, 0, 0); \
    acc2 = __builtin_amdgcn_mfma_f32_16x16x32_bf16(av_.s, *(const short8*)&BB[5], acc2, 0, 0, 0); \
    av_.u[0] = pkmul(Xp[8], Yc2_); av_.u[1] = pkmul(Xp[9], Yc2_);              \
    av_.u[2] = pkmul(Xp[10], Yc2_); av_.u[3] = pkmul(Xp[11], Yc2_);            \
    acc0 = __builtin_amdgcn_mfma_f32_16x16x32_bf16(av_.s, *(const short8*)&BB[6], acc0, 0, 0, 0); \
    acc1 = __builtin_amdgcn_mfma_f32_16x16x32_bf16(av_.s, *(const short8*)&BB[7], acc1, 0, 0, 0); \
    acc2 = __builtin_amdgcn_mfma_f32_16x16x32_bf16(av_.s, *(const short8*)&BB[8], acc2, 0, 0, 0); \
} while (0)

__global__ __launch_bounds__(256, 2) void attn_kernel(
    const unsigned short* __restrict__ xtab, const unsigned short* __restrict__ ytab,
    const uint4* __restrict__ vhat, float* __restrict__ oattn)
{
    __shared__ unsigned short YsL[64 * 50];   // 6400 B (padded rows)
    __shared__ float linv_s[64];

    int blk = blockIdx.x;
    int qt = blk % 36;
    int ng = blk / 36;
    int nb = ng >> 3, g = ng & 7;
    int qbase = qt * 64;
    int t = threadIdx.x;
    int m = t >> 6, L = t & 63;

    // stage Y rows (64 q x 48 bf16 = 1536 uints)
    {
        const unsigned int* ysrc =
            (const unsigned int*)(ytab + ((size_t)ng * NPOS + qbase) * 48);
        #pragma unroll
        for (int i = 0; i < 6; ++i) {
            int s = t + i * 256;
            int row = s / 24, col = s - row * 24;
            *(unsigned int*)&YsL[row * 50 + col * 2] = ysrc[s];
        }
    }

    int qp = m * 16 + (L & 15);
    int o = L >> 4;
    const unsigned short* xrow = xtab + ((size_t)ng * NPOS + qbase + qp) * 48;
    unsigned int Xp[12];
    #pragma unroll
    for (int c = 0; c < 3; ++c)
        #pragma unroll
        for (int jj = 0; jj < 4; ++jj) {
            int k = c * 32 + o * 8 + jj * 2;
            int v0 = (k < 48) ? k : k - 48;
            Xp[c * 4 + jj] = *(const unsigned int*)(xrow + v0);
        }
    __syncthreads();

    floatx4 acc0 = {0.f, 0.f, 0.f, 0.f};
    floatx4 acc1 = {0.f, 0.f, 0.f, 0.f};
    floatx4 acc2 = {0.f, 0.f, 0.f, 0.f};

    const uint4* vb = vhat + (size_t)ng * 24 * 576 + L;
    uint4 Abuf[9], Bbuf[9];
    #pragma unroll
    for (int gg = 0; gg < 9; ++gg) Abuf[gg] = vb[gg * 64];

    for (int tile = 0; tile < 24; tile += 2) {
        const uint4* sB = vb + (tile + 1) * 576;
        #pragma unroll
        for (int gg = 0; gg < 9; ++gg) Bbuf[gg] = sB[gg * 64];
        DO_TILE(Abuf, tile);
        if (tile + 2 < 24) {
            const uint4* sA = vb + (tile + 2) * 576;
            #pragma unroll
            for (int gg = 0; gg < 9; ++gg) Abuf[gg] = sA[gg * 64];
        }
        DO_TILE(Bbuf, tile + 1);
    }

    // ---- epilogue: l from acc2 col 0, normalize, store ----
    if ((L & 15) == 0) {
        int qc = m * 16 + (L >> 4) * 4;
        #pragma unroll
        for (int r = 0; r < 4; ++r)
            linv_s[qc + r] = 1.0f / acc2[r];
    }
    __syncthreads();
    {
        int qc = m * 16 + (L >> 4) * 4;
        float4 li = *(const float4*)&linv_s[qc];
        int d0 = L & 15;
        float* r0 = oattn + ((size_t)(nb * 256 + g * 32 + d0)) * NPOS + qbase + qc;
        *(float4*)r0 = make_float4(acc0[0] * li.x, acc0[1] * li.y,
                                   acc0[2] * li.z, acc0[3] * li.w);
        float* r1 = oattn + ((size_t)(nb * 256 + g * 32 + 16 + d0)) * NPOS + qbase + qc;
        *(float4*)r1 = make_float4(acc1[0] * li.x, acc1[1] * li.y,
                                   acc1[2] * li.z, acc1[3] * li.w);
    }
}

// ---------------------------------------------------------------------------
// Kernel 5: output projection GEMM
// ---------------------------------------------------------------------------
__global__ __launch_bounds__(256) void proj_kernel(
    const float* __restrict__ oattn, const float* __restrict__ Wp,
    const float* __restrict__ bpv, float* __restrict__ proj)
{
    __shared__ float As[16][64];
    __shared__ float Bs[16][64];
    int mTile = blockIdx.x;   // 0..3
    int nTile = blockIdx.y;   // 0..71
    int t = threadIdx.x;
    int tx = t & 15, ty = t >> 4;
    int colBase = nTile * 64;
    int n = colBase / NPOS;
    int pBase = colBase - n * NPOS;

    int lo = t & 63;
    int lc = (t >> 6) * 4;
    int bc = t >> 4;
    int bp = (t & 15) * 4;

    float acc[4][4] = {};

    for (int k0 = 0; k0 < 256; k0 += 16) {
        int o = mTile * 64 + lo;
        float4 w4 = *(const float4*)(Wp + o * 256 + k0 + lc);
        As[lc + 0][lo] = w4.x;
        As[lc + 1][lo] = w4.y;
        As[lc + 2][lo] = w4.z;
        As[lc + 3][lo] = w4.w;
        int c = k0 + bc;
        *(float4*)&Bs[bc][bp] =
            *(const float4*)(oattn + ((size_t)(n * 256 + c)) * NPOS + pBase + bp);
        __syncthreads();
        #pragma unroll
        for (int kk = 0; kk < 16; ++kk) {
            float4 av = *(const float4*)&As[kk][ty * 4];
            float4 b4 = *(const float4*)&Bs[kk][tx * 4];
            float a[4] = {av.x, av.y, av.z, av.w};
            float bb[4] = {b4.x, b4.y, b4.z, b4.w};
            #pragma unroll
            for (int i = 0; i < 4; ++i)
                #pragma unroll
                for (int j = 0; j < 4; ++j)
                    acc[i][j] += a[i] * bb[j];
        }
        __syncthreads();
    }

    #pragma unroll
    for (int i = 0; i < 4; ++i) {
        int o = mTile * 64 + ty * 4 + i;
        float bias = bpv[o];
        *(float4*)(proj + ((size_t)(n * 256 + o)) * NPOS + pBase + tx * 4) =
            make_float4(acc[i][0] + bias, acc[i][1] + bias,
                        acc[i][2] + bias, acc[i][3] + bias);
    }
}

// ---------------------------------------------------------------------------
// Kernel 6: bilinear 48->96 upsample + residual
// ---------------------------------------------------------------------------
__global__ __launch_bounds__(256) void resize_kernel(
    const float* __restrict__ proj, const float* __restrict__ x,
    const float* __restrict__ gamma, float* __restrict__ out)
{
    int idx = blockIdx.x * 256 + threadIdx.x;
    int J = idx % 96;
    int tmp = idx / 96;
    int I = tmp % 96;
    int nc = tmp / 96;

    int jr = I >> 1;
    int r0, r1; float w0, w1;
    if ((I & 1) == 0) { r0 = (jr > 0) ? jr - 1 : 0; r1 = jr; w0 = 0.25f; w1 = 0.75f; }
    else              { r0 = jr; r1 = (jr < 47) ? jr + 1 : 47; w0 = 0.75f; w1 = 0.25f; }
    int jc = J >> 1;
    int c0, c1; float u0, u1;
    if ((J & 1) == 0) { c0 = (jc > 0) ? jc - 1 : 0; c1 = jc; u0 = 0.25f; u1 = 0.75f; }
    else              { c0 = jc; c1 = (jc < 47) ? jc + 1 : 47; u0 = 0.75f; u1 = 0.25f; }

    const float* P = proj + (size_t)nc * NPOS;
    float v = w0 * (u0 * P[r0 * 48 + c0] + u1 * P[r0 * 48 + c1]) +
              w1 * (u0 * P[r1 * 48 + c0] + u1 * P[r1 * 48 + c1]);
    out[idx] = gamma[0] * v + x[idx];
}

// ---------------------------------------------------------------------------
extern "C" void kernel_launch(void* const* d_in, const int* in_sizes, int n_in,
                              void* d_out, int out_size, void* d_ws, size_t ws_size,
                              hipStream_t stream)
{
    const float* x     = (const float*)d_in[0];
    const float* Wq    = (const float*)d_in[1];
    const float* Wk    = (const float*)d_in[2];
    const float* Wv    = (const float*)d_in[3];
    const float* Wx    = (const float*)d_in[4];
    const float* Wy    = (const float*)d_in[5];
    const float* ab    = (const float*)d_in[6];
    const float* Wp    = (const float*)d_in[7];
    const float* bp    = (const float*)d_in[8];
    const float* gamma = (const float*)d_in[9];
    float* out = (float*)d_out;

    float* ws = (float*)d_ws;
    float* posx  = ws;                               // 95*256
    float* posy  = posx + 95 * 256;                  // 95*256
    float* wkeff = posy + 95 * 256;                  // 8*256
    float* qbuf  = wkeff + 8 * 256;                  // 2*8*2304*32  [ng][p][32]
    float* vbuf  = qbuf + 2 * 8 * NPOS * 32;         // 2*8*2304*32  [n][256][p]
    float* ekA   = vbuf + 2 * 8 * NPOS * 32;         // 2*8*2304
    float* oattn = ekA + 2 * 8 * NPOS;               // 2*256*2304
    float* proj  = oattn + 2 * 256 * NPOS;           // 2*256*2304
    unsigned short* xtab = (unsigned short*)(proj + 2 * 256 * NPOS);  // 16*2304*48 bf16
    unsigned short* ytab = xtab + 16 * NPOS * 48;                     // 16*2304*48 bf16
    // Aliases (stream-ordered lifetimes):
    //   xs (extract output, dead after qkv) aliases oattn
    //   vhat (dead after attn) aliases proj
    float* xs    = oattn;
    uint4* vhat  = (uint4*)proj;

    hipLaunchKernelGGL(pos_tables_kernel, dim3(103), dim3(256), 0, stream,
                       Wx, Wy, Wk, ab, posx, posy, wkeff);
    hipLaunchKernelGGL(extract_kernel, dim3(1152), dim3(256), 0, stream, x, xs);
    hipLaunchKernelGGL(qkv_kernel, dim3(9, 72), dim3(256), 0, stream,
                       xs, Wq, Wv, wkeff, qbuf, vbuf, ekA);
    hipLaunchKernelGGL(softA_kernel, dim3(16), dim3(256), 0, stream, ekA);
    hipLaunchKernelGGL(vhat_kernel, dim3(24, 16), dim3(256), 0, stream,
                       vbuf, ekA, vhat);
    hipLaunchKernelGGL(exy_kernel, dim3(16 * 72), dim3(256), 0, stream,
                       qbuf, posx, posy, xtab, ytab);
    hipLaunchKernelGGL(attn_kernel, dim3(576), dim3(256), 0, stream,
                       xtab, ytab, vhat, oattn);
    hipLaunchKernelGGL(proj_kernel, dim3(4, 72), dim3(256), 0, stream,
                       oattn, Wp, bp, proj);
    hipLaunchKernelGGL(resize_kernel, dim3((2 * 256 * 96 * 96) / 256), dim3(256), 0, stream,
                       proj, x, gamma, out);
}

// Round 8
// 187.620 us; speedup vs baseline: 1.3241x; 1.2793x over previous
//
#include <hip/hip_runtime.h>
#include <hip/hip_bf16.h>
#include <math.h>

// Problem constants
#define NB 2
#define CC 256
#define NPOS 2304   // 48*48
#define NDELTA 95

typedef __attribute__((ext_vector_type(8))) short short8;
typedef __attribute__((ext_vector_type(4))) float floatx4;

__device__ inline unsigned short f2bf(float x) {
    unsigned int u = __float_as_uint(x);
    u = (u + 0x7FFFu + ((u >> 16) & 1u)) >> 16;
    return (unsigned short)u;
}
__device__ inline unsigned int pk2(float a, float b) {
    return (unsigned int)f2bf(a) | ((unsigned int)f2bf(b) << 16);
}
__device__ inline unsigned int pkmul(unsigned int a, unsigned int b) {
    __hip_bfloat162 x = *(__hip_bfloat162*)&a;
    __hip_bfloat162 y = *(__hip_bfloat162*)&b;
    __hip_bfloat162 r = __hmul2(x, y);
    return *(unsigned int*)&r;
}

// ---------------------------------------------------------------------------
// Kernel 1: bf16 pos tables posxb/posyb[8 g][96 δ][32 d] + wk_eff[8][256].
// Grid 104: b<95 -> δ rows; b<103 -> wk_eff; b==103 -> zero δ=95 row.
// ---------------------------------------------------------------------------
__global__ __launch_bounds__(256) void pos_tables_kernel(
    const float* __restrict__ Wx, const float* __restrict__ Wy,
    const float* __restrict__ Wk, const float* __restrict__ ab,
    unsigned short* __restrict__ posxb, unsigned short* __restrict__ posyb,
    float* __restrict__ wkeff)
{
    int b = blockIdx.x;
    int t = threadIdx.x;
    if (b < NDELTA) {
        __shared__ float emb[128];
        float delta = (float)(b - 47);
        if (t < 64) {
            float dim_inv = exp2f(-(float)t * 0.15571537944784511f); // log2(1000)/64
            float ang = 2.0f * delta * dim_inv;
            emb[t]      = sinf(ang);
            emb[t + 64] = cosf(ang);
        }
        __syncthreads();
        float sx = 0.f, sy = 0.f;
        const float* wxr = Wx + t * 128;
        const float* wyr = Wy + t * 128;
        for (int f = 0; f < 128; ++f) {
            float e = emb[f];
            sx += e * wxr[f];
            sy += e * wyr[f];
        }
        const float inv_sqrt2 = 0.70710678118654752440f;
        int g = t >> 5, d = t & 31;
        posxb[((size_t)g * 96 + b) * 32 + d] = f2bf(sx * inv_sqrt2);
        posyb[((size_t)g * 96 + b) * 32 + d] = f2bf(sy * inv_sqrt2);
    } else if (b < NDELTA + 8) {
        int g = b - NDELTA;
        float s = 0.f;
        for (int d = 0; d < 32; ++d)
            s += ab[g * 32 + d] * Wk[(g * 32 + d) * 256 + t];
        wkeff[g * 256 + t] = s;
    } else {
        // zero the δ=95 pad row for all 8 g (256 threads = 8*32 exactly)
        int g = t >> 5, d = t & 31;
        posxb[((size_t)g * 96 + 95) * 32 + d] = 0;
        posyb[((size_t)g * 96 + 95) * 32 + d] = 0;
    }
}

// ---------------------------------------------------------------------------
// Kernel 1b: extract strided x into contiguous xs[n][c][48*48]
// ---------------------------------------------------------------------------
__global__ __launch_bounds__(256) void extract_kernel(
    const float* __restrict__ x, float* __restrict__ xs)
{
    int idx = blockIdx.x * 256 + threadIdx.x;
    int f = idx * 4;
    int nc = f / NPOS;
    int rem = f - nc * NPOS;
    int i = rem / 48, j = rem - i * 48;
    const float* row = x + (size_t)nc * (96 * 96) + (2 * i) * 96 + 2 * j;
    *(float4*)(xs + f) = make_float4(row[0], row[2], row[4], row[6]);
}

// ---------------------------------------------------------------------------
// Kernel 2: fused Q/V/e_key projection GEMM (B = contiguous xs).
// qbuf is written as bf16 [ng][p][32] (it only feeds bf16 MFMAs downstream).
// ---------------------------------------------------------------------------
__global__ __launch_bounds__(256) void qkv_kernel(
    const float* __restrict__ xs, const float* __restrict__ Wq,
    const float* __restrict__ Wv, const float* __restrict__ wkeff,
    unsigned short* __restrict__ qbuf, float* __restrict__ vbuf,
    float* __restrict__ ek)
{
    __shared__ float As[16][64];
    __shared__ float Bs[16][64];
    int mTile = blockIdx.x;   // 0..8
    int nTile = blockIdx.y;   // 0..71
    int t = threadIdx.x;
    int tx = t & 15, ty = t >> 4;
    int colBase = nTile * 64;
    int n = colBase / NPOS;
    int pBase = colBase - n * NPOS;

    int lo = t & 63;
    int lc = (t >> 6) * 4;
    int bc = t >> 4;
    int bp = (t & 15) * 4;

    float acc[4][4] = {};

    for (int k0 = 0; k0 < 256; k0 += 16) {
        int o = mTile * 64 + lo;
        float4 w4 = make_float4(0.f, 0.f, 0.f, 0.f);
        if (o < 256)      w4 = *(const float4*)(Wq + o * 256 + k0 + lc);
        else if (o < 512) w4 = *(const float4*)(Wv + (o - 256) * 256 + k0 + lc);
        else if (o < 520) w4 = *(const float4*)(wkeff + (o - 512) * 256 + k0 + lc);
        As[lc + 0][lo] = w4.x;
        As[lc + 1][lo] = w4.y;
        As[lc + 2][lo] = w4.z;
        As[lc + 3][lo] = w4.w;

        int c = k0 + bc;
        *(float4*)&Bs[bc][bp] =
            *(const float4*)(xs + ((size_t)(n * 256 + c)) * NPOS + pBase + bp);
        __syncthreads();

        #pragma unroll
        for (int kk = 0; kk < 16; ++kk) {
            float4 av = *(const float4*)&As[kk][ty * 4];
            float4 b4 = *(const float4*)&Bs[kk][tx * 4];
            float a[4] = {av.x, av.y, av.z, av.w};
            float bb[4] = {b4.x, b4.y, b4.z, b4.w};
            #pragma unroll
            for (int i = 0; i < 4; ++i)
                #pragma unroll
                for (int j = 0; j < 4; ++j)
                    acc[i][j] += a[i] * bb[j];
        }
        __syncthreads();
    }

    #pragma unroll
    for (int i = 0; i < 4; ++i) {
        int o = mTile * 64 + ty * 4 + i;
        if (o >= 520) continue;
        int p0 = pBase + tx * 4;
        if (o < 256) {
            int g = o >> 5, d = o & 31;
            #pragma unroll
            for (int j = 0; j < 4; ++j)
                qbuf[((size_t)(n * 8 + g) * NPOS + p0 + j) * 32 + d] = f2bf(acc[i][j]);
        } else if (o < 512) {
            int o2 = o - 256;
            *(float4*)(vbuf + (size_t)(n * 256 + o2) * NPOS + p0) =
                make_float4(acc[i][0], acc[i][1], acc[i][2], acc[i][3]);
        } else {
            *(float4*)(ek + (size_t)(n * 8 + (o - 512)) * NPOS + p0) =
                make_float4(acc[i][0], acc[i][1], acc[i][2], acc[i][3]);
        }
    }
}

// ---------------------------------------------------------------------------
// Kernel 3: per-(n,g) A = exp(ek - max(ek)), in place.
// ---------------------------------------------------------------------------
__global__ __launch_bounds__(256) void softA_kernel(float* __restrict__ ekA)
{
    int ng = blockIdx.x;
    float* e = ekA + (size_t)ng * NPOS;
    int t = threadIdx.x;
    __shared__ float red[256];
    float m = -1e30f;
    for (int k = t; k < NPOS; k += 256) m = fmaxf(m, e[k]);
    red[t] = m;
    __syncthreads();
    for (int s = 128; s > 0; s >>= 1) {
        if (t < s) red[t] = fmaxf(red[t], red[t + s]);
        __syncthreads();
    }
    m = red[0];
    for (int k = t; k < NPOS; k += 256) e[k] = __expf(e[k] - m);
}

// ---------------------------------------------------------------------------
// Kernel 3b: V̂ = A*V in bf16 B-fragment order, once per (n,g).
// ---------------------------------------------------------------------------
__global__ __launch_bounds__(256) void vhat_kernel(
    const float* __restrict__ vbuf, const float* __restrict__ ekA,
    uint4* __restrict__ vhat)
{
    int tile = blockIdx.x;   // 0..23
    int ng = blockIdx.y;     // 0..15
    int k0 = tile * 96;
    int t = threadIdx.x;
    const float* vb = vbuf + (size_t)ng * 32 * NPOS;
    const float* Ab = ekA + (size_t)ng * NPOS;
    uint4* out = vhat + ((size_t)ng * 24 + tile) * 576;

    for (int s = t; s < 576; s += 256) {
        int grp = s >> 6;
        int Ls = s & 63;
        int cc = grp / 3;
        int nn = grp - cc * 3;
        int koct = cc * 32 + ((Ls >> 4) << 3);
        uint4 w = make_uint4(0u, 0u, 0u, 0u);
        if (nn < 2) {
            int d = nn * 16 + (Ls & 15);
            const float* vp = vb + (size_t)d * NPOS + k0 + koct;
            const float* ap = Ab + k0 + koct;
            float4 v0 = *(const float4*)vp;
            float4 v1 = *(const float4*)(vp + 4);
            float4 a0 = *(const float4*)ap;
            float4 a1 = *(const float4*)(ap + 4);
            w.x = pk2(v0.x * a0.x, v0.y * a0.y);
            w.y = pk2(v0.z * a0.z, v0.w * a0.w);
            w.z = pk2(v1.x * a1.x, v1.y * a1.y);
            w.w = pk2(v1.z * a1.z, v1.w * a1.w);
        } else if ((Ls & 15) == 0) {
            const float* ap = Ab + k0 + koct;
            float4 a0 = *(const float4*)ap;
            float4 a1 = *(const float4*)(ap + 4);
            w.x = pk2(a0.x, a0.y);
            w.y = pk2(a0.z, a0.w);
            w.z = pk2(a1.x, a1.y);
            w.w = pk2(a1.z, a1.w);
        }
        out[s] = w;
    }
}

// ---------------------------------------------------------------------------
// Kernel 4: attention. Prologue: X/Y via MFMA (T = Q·pos^T, 6 tiles of
// 16x16 δ per table per wave) + exp -> LDS. K-loop: unroll-by-2 register
// prefetch MFMA as round 7.
// ---------------------------------------------------------------------------
#define DO_TILE(BB, TT) do {                                                   \
    int u0_ = (TT) * 2;                                                        \
    unsigned int y0_ = Ys[qp * 50 + u0_];     y0_ |= y0_ << 16;                \
    unsigned int y1_ = Ys[qp * 50 + u0_ + 1]; y1_ |= y1_ << 16;                \
    unsigned int Yc0_ = y0_, Yc1_ = (o < 2) ? y0_ : y1_, Yc2_ = y1_;           \
    union { unsigned int u[4]; short8 s; } av_;                                \
    av_.u[0] = pkmul(Xp[0], Yc0_); av_.u[1] = pkmul(Xp[1], Yc0_);              \
    av_.u[2] = pkmul(Xp[2], Yc0_); av_.u[3] = pkmul(Xp[3], Yc0_);              \
    acc0 = __builtin_amdgcn_mfma_f32_16x16x32_bf16(av_.s, *(const short8*)&BB[0], acc0, 0, 0, 0); \
    acc1 = __builtin_amdgcn_mfma_f32_16x16x32_bf16(av_.s, *(const short8*)&BB[1], acc1, 0, 0, 0); \
    acc2 = __builtin_amdgcn_mfma_f32_16x16x32_bf16(av_.s, *(const short8*)&BB[2], acc2, 0, 0, 0); \
    av_.u[0] = pkmul(Xp[4], Yc1_); av_.u[1] = pkmul(Xp[5], Yc1_);              \
    av_.u[2] = pkmul(Xp[6], Yc1_); av_.u[3] = pkmul(Xp[7], Yc1_);              \
    acc0 = __builtin_amdgcn_mfma_f32_16x16x32_bf16(av_.s, *(const short8*)&BB[3], acc0, 0, 0, 0); \
    acc1 = __builtin_amdgcn_mfma_f32_16x16x32_bf16(av_.s, *(const short8*)&BB[4], acc1, 0, 0, 0); \
    acc2 = __builtin_amdgcn_mfma_f32_16x16x32_bf16(av_.s, *(const short8*)&BB[5], acc2, 0, 0, 0); \
    av_.u[0] = pkmul(Xp[8], Yc2_); av_.u[1] = pkmul(Xp[9], Yc2_);              \
    av_.u[2] = pkmul(Xp[10], Yc2_); av_.u[3] = pkmul(Xp[11], Yc2_);            \
    acc0 = __builtin_amdgcn_mfma_f32_16x16x32_bf16(av_.s, *(const short8*)&BB[6], acc0, 0, 0, 0); \
    acc1 = __builtin_amdgcn_mfma_f32_16x16x32_bf16(av_.s, *(const short8*)&BB[7], acc1, 0, 0, 0); \
    acc2 = __builtin_amdgcn_mfma_f32_16x16x32_bf16(av_.s, *(const short8*)&BB[8], acc2, 0, 0, 0); \
} while (0)

__global__ __launch_bounds__(256, 2) void attn_kernel(
    const unsigned short* __restrict__ qbuf, const unsigned short* __restrict__ posxb,
    const unsigned short* __restrict__ posyb, const uint4* __restrict__ vhat,
    float* __restrict__ oattn)
{
    __shared__ unsigned short Xs[64 * 50];   // 6400 B
    __shared__ unsigned short Ys[64 * 50];   // 6400 B
    __shared__ float linv_s[64];

    int blk = blockIdx.x;
    int qt = blk % 36;
    int ng = blk / 36;
    int nb = ng >> 3, g = ng & 7;
    int qbase = qt * 64;
    int t = threadIdx.x;
    int m = t >> 6, L = t & 63;
    int l16 = L & 15, oct = L >> 4;

    // ---- prologue: T = Q·pos^T via MFMA, X/Y = exp(T) into LDS ----
    {
        int qtile0 = qbase + m * 16;          // 16-aligned, never crosses h-row
        int hq = qtile0 / 48;
        int wq0 = qtile0 - hq * 48;
        // A-frag: lane holds Q[q = qtile0 + l16][d = oct*8 .. +8] (bf16)
        short8 aq = *(const short8*)(qbuf +
            ((size_t)ng * NPOS + qtile0 + l16) * 32 + oct * 8);
        const unsigned short* pxg = posxb + (size_t)g * 96 * 32;
        const unsigned short* pyg = posyb + (size_t)g * 96 * 32;
        floatx4 zero = {0.f, 0.f, 0.f, 0.f};
        #pragma unroll
        for (int j = 0; j < 6; ++j) {
            int dl = j * 16 + l16;            // δ for this lane's C column
            short8 bx = *(const short8*)(pxg + (size_t)dl * 32 + oct * 8);
            short8 by = *(const short8*)(pyg + (size_t)dl * 32 + oct * 8);
            floatx4 tx = __builtin_amdgcn_mfma_f32_16x16x32_bf16(aq, bx, zero, 0, 0, 0);
            floatx4 ty = __builtin_amdgcn_mfma_f32_16x16x32_bf16(aq, by, zero, 0, 0, 0);
            int u = hq + 47 - dl;             // q-independent
            bool uok = (u >= 0) && (u < 48);
            #pragma unroll
            for (int r = 0; r < 4; ++r) {
                int ql = oct * 4 + r;         // C row = local q
                int v = wq0 + ql + 47 - dl;
                if (v >= 0 && v < 48)
                    Xs[(m * 16 + ql) * 50 + v] = f2bf(__expf(tx[r]));
                if (uok)
                    Ys[(m * 16 + ql) * 50 + u] = f2bf(__expf(ty[r]));
            }
        }
    }
    __syncthreads();

    // ---- pack X pairs from LDS ----
    int qp = m * 16 + l16;
    int o = oct;
    unsigned int Xp[12];
    #pragma unroll
    for (int c = 0; c < 3; ++c)
        #pragma unroll
        for (int jj = 0; jj < 4; ++jj) {
            int k = c * 32 + o * 8 + jj * 2;
            int v0 = (k < 48) ? k : k - 48;
            Xp[c * 4 + jj] = *(const unsigned int*)&Xs[qp * 50 + v0];
        }

    floatx4 acc0 = {0.f, 0.f, 0.f, 0.f};
    floatx4 acc1 = {0.f, 0.f, 0.f, 0.f};
    floatx4 acc2 = {0.f, 0.f, 0.f, 0.f};

    const uint4* vb = vhat + (size_t)ng * 24 * 576 + L;
    uint4 Abuf[9], Bbuf[9];
    #pragma unroll
    for (int gg = 0; gg < 9; ++gg) Abuf[gg] = vb[gg * 64];

    for (int tile = 0; tile < 24; tile += 2) {
        const uint4* sB = vb + (tile + 1) * 576;
        #pragma unroll
        for (int gg = 0; gg < 9; ++gg) Bbuf[gg] = sB[gg * 64];
        DO_TILE(Abuf, tile);
        if (tile + 2 < 24) {
            const uint4* sA = vb + (tile + 2) * 576;
            #pragma unroll
            for (int gg = 0; gg < 9; ++gg) Abuf[gg] = sA[gg * 64];
        }
        DO_TILE(Bbuf, tile + 1);
    }

    // ---- epilogue: l from acc2 col 0, normalize, store ----
    if ((L & 15) == 0) {
        int qc = m * 16 + (L >> 4) * 4;
        #pragma unroll
        for (int r = 0; r < 4; ++r)
            linv_s[qc + r] = 1.0f / acc2[r];
    }
    __syncthreads();
    {
        int qc = m * 16 + (L >> 4) * 4;
        float4 li = *(const float4*)&linv_s[qc];
        int d0 = L & 15;
        float* r0 = oattn + ((size_t)(nb * 256 + g * 32 + d0)) * NPOS + qbase + qc;
        *(float4*)r0 = make_float4(acc0[0] * li.x, acc0[1] * li.y,
                                   acc0[2] * li.z, acc0[3] * li.w);
        float* r1 = oattn + ((size_t)(nb * 256 + g * 32 + 16 + d0)) * NPOS + qbase + qc;
        *(float4*)r1 = make_float4(acc1[0] * li.x, acc1[1] * li.y,
                                   acc1[2] * li.z, acc1[3] * li.w);
    }
}

// ---------------------------------------------------------------------------
// Kernel 5: output projection GEMM
// ---------------------------------------------------------------------------
__global__ __launch_bounds__(256) void proj_kernel(
    const float* __restrict__ oattn, const float* __restrict__ Wp,
    const float* __restrict__ bpv, float* __restrict__ proj)
{
    __shared__ float As[16][64];
    __shared__ float Bs[16][64];
    int mTile = blockIdx.x;   // 0..3
    int nTile = blockIdx.y;   // 0..71
    int t = threadIdx.x;
    int tx = t & 15, ty = t >> 4;
    int colBase = nTile * 64;
    int n = colBase / NPOS;
    int pBase = colBase - n * NPOS;

    int lo = t & 63;
    int lc = (t >> 6) * 4;
    int bc = t >> 4;
    int bp = (t & 15) * 4;

    float acc[4][4] = {};

    for (int k0 = 0; k0 < 256; k0 += 16) {
        int o = mTile * 64 + lo;
        float4 w4 = *(const float4*)(Wp + o * 256 + k0 + lc);
        As[lc + 0][lo] = w4.x;
        As[lc + 1][lo] = w4.y;
        As[lc + 2][lo] = w4.z;
        As[lc + 3][lo] = w4.w;
        int c = k0 + bc;
        *(float4*)&Bs[bc][bp] =
            *(const float4*)(oattn + ((size_t)(n * 256 + c)) * NPOS + pBase + bp);
        __syncthreads();
        #pragma unroll
        for (int kk = 0; kk < 16; ++kk) {
            float4 av = *(const float4*)&As[kk][ty * 4];
            float4 b4 = *(const float4*)&Bs[kk][tx * 4];
            float a[4] = {av.x, av.y, av.z, av.w};
            float bb[4] = {b4.x, b4.y, b4.z, b4.w};
            #pragma unroll
            for (int i = 0; i < 4; ++i)
                #pragma unroll
                for (int j = 0; j < 4; ++j)
                    acc[i][j] += a[i] * bb[j];
        }
        __syncthreads();
    }

    #pragma unroll
    for (int i = 0; i < 4; ++i) {
        int o = mTile * 64 + ty * 4 + i;
        float bias = bpv[o];
        *(float4*)(proj + ((size_t)(n * 256 + o)) * NPOS + pBase + tx * 4) =
            make_float4(acc[i][0] + bias, acc[i][1] + bias,
                        acc[i][2] + bias, acc[i][3] + bias);
    }
}

// ---------------------------------------------------------------------------
// Kernel 6: bilinear 48->96 upsample + residual
// ---------------------------------------------------------------------------
__global__ __launch_bounds__(256) void resize_kernel(
    const float* __restrict__ proj, const float* __restrict__ x,
    const float* __restrict__ gamma, float* __restrict__ out)
{
    int idx = blockIdx.x * 256 + threadIdx.x;
    int J = idx % 96;
    int tmp = idx / 96;
    int I = tmp % 96;
    int nc = tmp / 96;

    int jr = I >> 1;
    int r0, r1; float w0, w1;
    if ((I & 1) == 0) { r0 = (jr > 0) ? jr - 1 : 0; r1 = jr; w0 = 0.25f; w1 = 0.75f; }
    else              { r0 = jr; r1 = (jr < 47) ? jr + 1 : 47; w0 = 0.75f; w1 = 0.25f; }
    int jc = J >> 1;
    int c0, c1; float u0, u1;
    if ((J & 1) == 0) { c0 = (jc > 0) ? jc - 1 : 0; c1 = jc; u0 = 0.25f; u1 = 0.75f; }
    else              { c0 = jc; c1 = (jc < 47) ? jc + 1 : 47; u0 = 0.75f; u1 = 0.25f; }

    const float* P = proj + (size_t)nc * NPOS;
    float v = w0 * (u0 * P[r0 * 48 + c0] + u1 * P[r0 * 48 + c1]) +
              w1 * (u0 * P[r1 * 48 + c0] + u1 * P[r1 * 48 + c1]);
    out[idx] = gamma[0] * v + x[idx];
}

// ---------------------------------------------------------------------------
extern "C" void kernel_launch(void* const* d_in, const int* in_sizes, int n_in,
                              void* d_out, int out_size, void* d_ws, size_t ws_size,
                              hipStream_t stream)
{
    const float* x     = (const float*)d_in[0];
    const float* Wq    = (const float*)d_in[1];
    const float* Wk    = (const float*)d_in[2];
    const float* Wv    = (const float*)d_in[3];
    const float* Wx    = (const float*)d_in[4];
    const float* Wy    = (const float*)d_in[5];
    const float* ab    = (const float*)d_in[6];
    const float* Wp    = (const float*)d_in[7];
    const float* bp    = (const float*)d_in[8];
    const float* gamma = (const float*)d_in[9];
    float* out = (float*)d_out;

    float* ws = (float*)d_ws;
    unsigned short* posxb = (unsigned short*)ws;          // 8*96*32 bf16
    unsigned short* posyb = posxb + 8 * 96 * 32;          // 8*96*32 bf16
    float* wkeff = ws + 2 * (8 * 96 * 32) / 2;            // 8*256 fp32 (after 2 bf16 tabs)
    unsigned short* qbuf = (unsigned short*)(wkeff + 8 * 256);  // 2*8*2304*32 bf16
    float* vbuf  = (float*)(qbuf + (size_t)2 * 8 * NPOS * 32);  // 2*8*2304*32 fp32
    float* ekA   = vbuf + (size_t)2 * 8 * NPOS * 32;      // 2*8*2304
    float* oattn = ekA + 2 * 8 * NPOS;                    // 2*256*2304
    float* proj  = oattn + (size_t)2 * 256 * NPOS;        // 2*256*2304
    // Aliases (stream-ordered lifetimes):
    float* xs    = oattn;          // extract output, dead after qkv
    uint4* vhat  = (uint4*)proj;   // dead after attn; 3.54 MB <= proj 4.72 MB

    hipLaunchKernelGGL(pos_tables_kernel, dim3(104), dim3(256), 0, stream,
                       Wx, Wy, Wk, ab, posxb, posyb, wkeff);
    hipLaunchKernelGGL(extract_kernel, dim3(1152), dim3(256), 0, stream, x, xs);
    hipLaunchKernelGGL(qkv_kernel, dim3(9, 72), dim3(256), 0, stream,
                       xs, Wq, Wv, wkeff, qbuf, vbuf, ekA);
    hipLaunchKernelGGL(softA_kernel, dim3(16), dim3(256), 0, stream, ekA);
    hipLaunchKernelGGL(vhat_kernel, dim3(24, 16), dim3(256), 0, stream,
                       vbuf, ekA, vhat);
    hipLaunchKernelGGL(attn_kernel, dim3(576), dim3(256), 0, stream,
                       qbuf, posxb, posyb, vhat, oattn);
    hipLaunchKernelGGL(proj_kernel, dim3(4, 72), dim3(256), 0, stream,
                       oattn, Wp, bp, proj);
    hipLaunchKernelGGL(resize_kernel, dim3((2 * 256 * 96 * 96) / 256), dim3(256), 0, stream,
                       proj, x, gamma, out);
}

// Round 9
// 171.249 us; speedup vs baseline: 1.4507x; 1.0956x over previous
//
#include <hip/hip_runtime.h>
#include <hip/hip_bf16.h>
#include <math.h>

// Problem constants
#define NB 2
#define CC 256
#define NPOS 2304   // 48*48
#define NDELTA 95

typedef __attribute__((ext_vector_type(8))) short short8;
typedef __attribute__((ext_vector_type(4))) float floatx4;

__device__ inline unsigned short f2bf(float x) {
    unsigned int u = __float_as_uint(x);
    u = (u + 0x7FFFu + ((u >> 16) & 1u)) >> 16;
    return (unsigned short)u;
}
__device__ inline unsigned int pk2(float a, float b) {
    return (unsigned int)f2bf(a) | ((unsigned int)f2bf(b) << 16);
}
__device__ inline unsigned int pkmul(unsigned int a, unsigned int b) {
    __hip_bfloat162 x = *(__hip_bfloat162*)&a;
    __hip_bfloat162 y = *(__hip_bfloat162*)&b;
    __hip_bfloat162 r = __hmul2(x, y);
    return *(unsigned int*)&r;
}

// ---------------------------------------------------------------------------
// Kernel 1: bf16 pos tables posxb/posyb[8 g][96 δ][32 d] + wk_eff[8][256].
// ---------------------------------------------------------------------------
__global__ __launch_bounds__(256) void pos_tables_kernel(
    const float* __restrict__ Wx, const float* __restrict__ Wy,
    const float* __restrict__ Wk, const float* __restrict__ ab,
    unsigned short* __restrict__ posxb, unsigned short* __restrict__ posyb,
    float* __restrict__ wkeff)
{
    int b = blockIdx.x;
    int t = threadIdx.x;
    if (b < NDELTA) {
        __shared__ float emb[128];
        float delta = (float)(b - 47);
        if (t < 64) {
            float dim_inv = exp2f(-(float)t * 0.15571537944784511f); // log2(1000)/64
            float ang = 2.0f * delta * dim_inv;
            emb[t]      = sinf(ang);
            emb[t + 64] = cosf(ang);
        }
        __syncthreads();
        float sx = 0.f, sy = 0.f;
        const float* wxr = Wx + t * 128;
        const float* wyr = Wy + t * 128;
        for (int f = 0; f < 128; ++f) {
            float e = emb[f];
            sx += e * wxr[f];
            sy += e * wyr[f];
        }
        const float inv_sqrt2 = 0.70710678118654752440f;
        int g = t >> 5, d = t & 31;
        posxb[((size_t)g * 96 + b) * 32 + d] = f2bf(sx * inv_sqrt2);
        posyb[((size_t)g * 96 + b) * 32 + d] = f2bf(sy * inv_sqrt2);
    } else if (b < NDELTA + 8) {
        int g = b - NDELTA;
        float s = 0.f;
        for (int d = 0; d < 32; ++d)
            s += ab[g * 32 + d] * Wk[(g * 32 + d) * 256 + t];
        wkeff[g * 256 + t] = s;
    } else {
        int g = t >> 5, d = t & 31;
        posxb[((size_t)g * 96 + 95) * 32 + d] = 0;
        posyb[((size_t)g * 96 + 95) * 32 + d] = 0;
    }
}

// ---------------------------------------------------------------------------
// Kernel 1b: extract strided x into contiguous xs[n][c][48*48] (fp32)
// ---------------------------------------------------------------------------
__global__ __launch_bounds__(256) void extract_kernel(
    const float* __restrict__ x, float* __restrict__ xs)
{
    int idx = blockIdx.x * 256 + threadIdx.x;
    int f = idx * 4;
    int nc = f / NPOS;
    int rem = f - nc * NPOS;
    int i = rem / 48, j = rem - i * 48;
    const float* row = x + (size_t)nc * (96 * 96) + (2 * i) * 96 + 2 * j;
    *(float4*)(xs + f) = make_float4(row[0], row[2], row[4], row[6]);
}

// ---------------------------------------------------------------------------
// Kernel 1c: bf16 weight copies. Wb[576][256] (Wq|Wv|wkeff|zeros),
// Wpb[256][256]. Grid 832, one row per block.
// ---------------------------------------------------------------------------
__global__ __launch_bounds__(256) void wconv_kernel(
    const float* __restrict__ Wq, const float* __restrict__ Wv,
    const float* __restrict__ wkeff, const float* __restrict__ Wp,
    unsigned short* __restrict__ Wb, unsigned short* __restrict__ Wpb)
{
    int o = blockIdx.x;
    int t = threadIdx.x;
    if (o < 576) {
        float v = 0.f;
        if (o < 256)      v = Wq[o * 256 + t];
        else if (o < 512) v = Wv[(o - 256) * 256 + t];
        else if (o < 520) v = wkeff[(o - 512) * 256 + t];
        Wb[(size_t)o * 256 + t] = f2bf(v);
    } else {
        int o2 = o - 576;
        Wpb[(size_t)o2 * 256 + t] = f2bf(Wp[o2 * 256 + t]);
    }
}

// ---------------------------------------------------------------------------
// Kernel 2: Q/V/e_key projection via bf16 MFMA.
// C[o,p] = Wb[o,:]·xs[:,p]. Block = 4 waves; wave = M16 x N64; K=256.
// A-frag: direct global 16B load from Wb. B: LDS transpose staging
// (32k x 64p fp32 -> bf16 [p][k] pad 40) -> one ds_read_b128 per frag.
// ---------------------------------------------------------------------------
__global__ __launch_bounds__(256) void qkv_kernel(
    const float* __restrict__ xs, const unsigned short* __restrict__ Wb,
    unsigned short* __restrict__ qbuf, float* __restrict__ vbuf,
    float* __restrict__ ek)
{
    __shared__ __align__(16) unsigned short Bt[64 * 40];
    int mTile = blockIdx.x;   // 0..8
    int nTile = blockIdx.y;   // 0..71
    int t = threadIdx.x;
    int m = t >> 6, L = t & 63, l16 = L & 15, oct = L >> 4;
    int colBase = nTile * 64;
    int n = colBase / NPOS;
    int p0 = colBase - n * NPOS;
    int o0 = mTile * 64 + m * 16;

    floatx4 acc[4] = {{0,0,0,0},{0,0,0,0},{0,0,0,0},{0,0,0,0}};

    int sc = t >> 4;            // staging c-row 0..15
    int sp = (t & 15) * 4;      // staging p quad
    for (int k0 = 0; k0 < 256; k0 += 32) {
        __syncthreads();        // prior MFMA reads of Bt done
        #pragma unroll
        for (int i = 0; i < 2; ++i) {
            int c = k0 + i * 16 + sc;
            float4 v = *(const float4*)(xs + ((size_t)(n * 256 + c)) * NPOS + p0 + sp);
            int cl = i * 16 + sc;
            Bt[(sp + 0) * 40 + cl] = f2bf(v.x);
            Bt[(sp + 1) * 40 + cl] = f2bf(v.y);
            Bt[(sp + 2) * 40 + cl] = f2bf(v.z);
            Bt[(sp + 3) * 40 + cl] = f2bf(v.w);
        }
        short8 a = *(const short8*)(Wb + (size_t)(o0 + l16) * 256 + k0 + oct * 8);
        __syncthreads();        // Bt visible
        #pragma unroll
        for (int f = 0; f < 4; ++f) {
            short8 b = *(const short8*)&Bt[(f * 16 + l16) * 40 + oct * 8];
            acc[f] = __builtin_amdgcn_mfma_f32_16x16x32_bf16(a, b, acc[f], 0, 0, 0);
        }
    }

    #pragma unroll
    for (int f = 0; f < 4; ++f) {
        int p = p0 + f * 16 + l16;
        #pragma unroll
        for (int r = 0; r < 4; ++r) {
            int o = o0 + oct * 4 + r;
            float val = acc[f][r];
            if (o < 256) {
                int g = o >> 5, d = o & 31;
                qbuf[((size_t)(n * 8 + g) * NPOS + p) * 32 + d] = f2bf(val);
            } else if (o < 512) {
                vbuf[((size_t)(n * 256 + (o - 256))) * NPOS + p] = val;
            } else if (o < 520) {
                ek[((size_t)(n * 8 + (o - 512))) * NPOS + p] = val;
            }
        }
    }
}

// ---------------------------------------------------------------------------
// Kernel 3: per-(n,g) A = exp(ek - max(ek)), in place.
// ---------------------------------------------------------------------------
__global__ __launch_bounds__(256) void softA_kernel(float* __restrict__ ekA)
{
    int ng = blockIdx.x;
    float* e = ekA + (size_t)ng * NPOS;
    int t = threadIdx.x;
    __shared__ float red[256];
    float m = -1e30f;
    for (int k = t; k < NPOS; k += 256) m = fmaxf(m, e[k]);
    red[t] = m;
    __syncthreads();
    for (int s = 128; s > 0; s >>= 1) {
        if (t < s) red[t] = fmaxf(red[t], red[t + s]);
        __syncthreads();
    }
    m = red[0];
    for (int k = t; k < NPOS; k += 256) e[k] = __expf(e[k] - m);
}

// ---------------------------------------------------------------------------
// Kernel 3b: V̂ = A*V in bf16 B-fragment order, once per (n,g).
// ---------------------------------------------------------------------------
__global__ __launch_bounds__(256) void vhat_kernel(
    const float* __restrict__ vbuf, const float* __restrict__ ekA,
    uint4* __restrict__ vhat)
{
    int tile = blockIdx.x;   // 0..23
    int ng = blockIdx.y;     // 0..15
    int k0 = tile * 96;
    int t = threadIdx.x;
    const float* vb = vbuf + (size_t)ng * 32 * NPOS;
    const float* Ab = ekA + (size_t)ng * NPOS;
    uint4* out = vhat + ((size_t)ng * 24 + tile) * 576;

    for (int s = t; s < 576; s += 256) {
        int grp = s >> 6;
        int Ls = s & 63;
        int cc = grp / 3;
        int nn = grp - cc * 3;
        int koct = cc * 32 + ((Ls >> 4) << 3);
        uint4 w = make_uint4(0u, 0u, 0u, 0u);
        if (nn < 2) {
            int d = nn * 16 + (Ls & 15);
            const float* vp = vb + (size_t)d * NPOS + k0 + koct;
            const float* ap = Ab + k0 + koct;
            float4 v0 = *(const float4*)vp;
            float4 v1 = *(const float4*)(vp + 4);
            float4 a0 = *(const float4*)ap;
            float4 a1 = *(const float4*)(ap + 4);
            w.x = pk2(v0.x * a0.x, v0.y * a0.y);
            w.y = pk2(v0.z * a0.z, v0.w * a0.w);
            w.z = pk2(v1.x * a1.x, v1.y * a1.y);
            w.w = pk2(v1.z * a1.z, v1.w * a1.w);
        } else if ((Ls & 15) == 0) {
            const float* ap = Ab + k0 + koct;
            float4 a0 = *(const float4*)ap;
            float4 a1 = *(const float4*)(ap + 4);
            w.x = pk2(a0.x, a0.y);
            w.y = pk2(a0.z, a0.w);
            w.z = pk2(a1.x, a1.y);
            w.w = pk2(a1.z, a1.w);
        }
        out[s] = w;
    }
}

// ---------------------------------------------------------------------------
// Kernel 4: attention (unchanged from round 8).
// ---------------------------------------------------------------------------
#define DO_TILE(BB, TT) do {                                                   \
    int u0_ = (TT) * 2;                                                        \
    unsigned int y0_ = Ys[qp * 50 + u0_];     y0_ |= y0_ << 16;                \
    unsigned int y1_ = Ys[qp * 50 + u0_ + 1]; y1_ |= y1_ << 16;                \
    unsigned int Yc0_ = y0_, Yc1_ = (o < 2) ? y0_ : y1_, Yc2_ = y1_;           \
    union { unsigned int u[4]; short8 s; } av_;                                \
    av_.u[0] = pkmul(Xp[0], Yc0_); av_.u[1] = pkmul(Xp[1], Yc0_);              \
    av_.u[2] = pkmul(Xp[2], Yc0_); av_.u[3] = pkmul(Xp[3], Yc0_);              \
    acc0 = __builtin_amdgcn_mfma_f32_16x16x32_bf16(av_.s, *(const short8*)&BB[0], acc0, 0, 0, 0); \
    acc1 = __builtin_amdgcn_mfma_f32_16x16x32_bf16(av_.s, *(const short8*)&BB[1], acc1, 0, 0, 0); \
    acc2 = __builtin_amdgcn_mfma_f32_16x16x32_bf16(av_.s, *(const short8*)&BB[2], acc2, 0, 0, 0); \
    av_.u[0] = pkmul(Xp[4], Yc1_); av_.u[1] = pkmul(Xp[5], Yc1_);              \
    av_.u[2] = pkmul(Xp[6], Yc1_); av_.u[3] = pkmul(Xp[7], Yc1_);              \
    acc0 = __builtin_amdgcn_mfma_f32_16x16x32_bf16(av_.s, *(const short8*)&BB[3], acc0, 0, 0, 0); \
    acc1 = __builtin_amdgcn_mfma_f32_16x16x32_bf16(av_.s, *(const short8*)&BB[4], acc1, 0, 0, 0); \
    acc2 = __builtin_amdgcn_mfma_f32_16x16x32_bf16(av_.s, *(const short8*)&BB[5], acc2, 0, 0, 0); \
    av_.u[0] = pkmul(Xp[8], Yc2_); av_.u[1] = pkmul(Xp[9], Yc2_);              \
    av_.u[2] = pkmul(Xp[10], Yc2_); av_.u[3] = pkmul(Xp[11], Yc2_);            \
    acc0 = __builtin_amdgcn_mfma_f32_16x16x32_bf16(av_.s, *(const short8*)&BB[6], acc0, 0, 0, 0); \
    acc1 = __builtin_amdgcn_mfma_f32_16x16x32_bf16(av_.s, *(const short8*)&BB[7], acc1, 0, 0, 0); \
    acc2 = __builtin_amdgcn_mfma_f32_16x16x32_bf16(av_.s, *(const short8*)&BB[8], acc2, 0, 0, 0); \
} while (0)

__global__ __launch_bounds__(256, 2) void attn_kernel(
    const unsigned short* __restrict__ qbuf, const unsigned short* __restrict__ posxb,
    const unsigned short* __restrict__ posyb, const uint4* __restrict__ vhat,
    float* __restrict__ oattn)
{
    __shared__ unsigned short Xs[64 * 50];
    __shared__ unsigned short Ys[64 * 50];
    __shared__ float linv_s[64];

    int blk = blockIdx.x;
    int qt = blk % 36;
    int ng = blk / 36;
    int nb = ng >> 3, g = ng & 7;
    int qbase = qt * 64;
    int t = threadIdx.x;
    int m = t >> 6, L = t & 63;
    int l16 = L & 15, oct = L >> 4;

    // ---- prologue: T = Q·pos^T via MFMA, X/Y = exp(T) into LDS ----
    {
        int qtile0 = qbase + m * 16;
        int hq = qtile0 / 48;
        int wq0 = qtile0 - hq * 48;
        short8 aq = *(const short8*)(qbuf +
            ((size_t)ng * NPOS + qtile0 + l16) * 32 + oct * 8);
        const unsigned short* pxg = posxb + (size_t)g * 96 * 32;
        const unsigned short* pyg = posyb + (size_t)g * 96 * 32;
        floatx4 zero = {0.f, 0.f, 0.f, 0.f};
        #pragma unroll
        for (int j = 0; j < 6; ++j) {
            int dl = j * 16 + l16;
            short8 bx = *(const short8*)(pxg + (size_t)dl * 32 + oct * 8);
            short8 by = *(const short8*)(pyg + (size_t)dl * 32 + oct * 8);
            floatx4 tx = __builtin_amdgcn_mfma_f32_16x16x32_bf16(aq, bx, zero, 0, 0, 0);
            floatx4 ty = __builtin_amdgcn_mfma_f32_16x16x32_bf16(aq, by, zero, 0, 0, 0);
            int u = hq + 47 - dl;
            bool uok = (u >= 0) && (u < 48);
            #pragma unroll
            for (int r = 0; r < 4; ++r) {
                int ql = oct * 4 + r;
                int v = wq0 + ql + 47 - dl;
                if (v >= 0 && v < 48)
                    Xs[(m * 16 + ql) * 50 + v] = f2bf(__expf(tx[r]));
                if (uok)
                    Ys[(m * 16 + ql) * 50 + u] = f2bf(__expf(ty[r]));
            }
        }
    }
    __syncthreads();

    int qp = m * 16 + l16;
    int o = oct;
    unsigned int Xp[12];
    #pragma unroll
    for (int c = 0; c < 3; ++c)
        #pragma unroll
        for (int jj = 0; jj < 4; ++jj) {
            int k = c * 32 + o * 8 + jj * 2;
            int v0 = (k < 48) ? k : k - 48;
            Xp[c * 4 + jj] = *(const unsigned int*)&Xs[qp * 50 + v0];
        }

    floatx4 acc0 = {0.f, 0.f, 0.f, 0.f};
    floatx4 acc1 = {0.f, 0.f, 0.f, 0.f};
    floatx4 acc2 = {0.f, 0.f, 0.f, 0.f};

    const uint4* vb = vhat + (size_t)ng * 24 * 576 + L;
    uint4 Abuf[9], Bbuf[9];
    #pragma unroll
    for (int gg = 0; gg < 9; ++gg) Abuf[gg] = vb[gg * 64];

    for (int tile = 0; tile < 24; tile += 2) {
        const uint4* sB = vb + (tile + 1) * 576;
        #pragma unroll
        for (int gg = 0; gg < 9; ++gg) Bbuf[gg] = sB[gg * 64];
        DO_TILE(Abuf, tile);
        if (tile + 2 < 24) {
            const uint4* sA = vb + (tile + 2) * 576;
            #pragma unroll
            for (int gg = 0; gg < 9; ++gg) Abuf[gg] = sA[gg * 64];
        }
        DO_TILE(Bbuf, tile + 1);
    }

    if ((L & 15) == 0) {
        int qc = m * 16 + (L >> 4) * 4;
        #pragma unroll
        for (int r = 0; r < 4; ++r)
            linv_s[qc + r] = 1.0f / acc2[r];
    }
    __syncthreads();
    {
        int qc = m * 16 + (L >> 4) * 4;
        float4 li = *(const float4*)&linv_s[qc];
        int d0 = L & 15;
        float* r0 = oattn + ((size_t)(nb * 256 + g * 32 + d0)) * NPOS + qbase + qc;
        *(float4*)r0 = make_float4(acc0[0] * li.x, acc0[1] * li.y,
                                   acc0[2] * li.z, acc0[3] * li.w);
        float* r1 = oattn + ((size_t)(nb * 256 + g * 32 + 16 + d0)) * NPOS + qbase + qc;
        *(float4*)r1 = make_float4(acc1[0] * li.x, acc1[1] * li.y,
                                   acc1[2] * li.z, acc1[3] * li.w);
    }
}

// ---------------------------------------------------------------------------
// Kernel 5: output projection via bf16 MFMA (same structure as qkv_kernel).
// ---------------------------------------------------------------------------
__global__ __launch_bounds__(256) void proj_kernel(
    const float* __restrict__ oattn, const unsigned short* __restrict__ Wpb,
    const float* __restrict__ bpv, float* __restrict__ proj)
{
    __shared__ __align__(16) unsigned short Bt[64 * 40];
    int mTile = blockIdx.x;   // 0..3
    int nTile = blockIdx.y;   // 0..71
    int t = threadIdx.x;
    int m = t >> 6, L = t & 63, l16 = L & 15, oct = L >> 4;
    int colBase = nTile * 64;
    int n = colBase / NPOS;
    int p0 = colBase - n * NPOS;
    int o0 = mTile * 64 + m * 16;

    floatx4 acc[4] = {{0,0,0,0},{0,0,0,0},{0,0,0,0},{0,0,0,0}};

    int sc = t >> 4;
    int sp = (t & 15) * 4;
    for (int k0 = 0; k0 < 256; k0 += 32) {
        __syncthreads();
        #pragma unroll
        for (int i = 0; i < 2; ++i) {
            int c = k0 + i * 16 + sc;
            float4 v = *(const float4*)(oattn + ((size_t)(n * 256 + c)) * NPOS + p0 + sp);
            int cl = i * 16 + sc;
            Bt[(sp + 0) * 40 + cl] = f2bf(v.x);
            Bt[(sp + 1) * 40 + cl] = f2bf(v.y);
            Bt[(sp + 2) * 40 + cl] = f2bf(v.z);
            Bt[(sp + 3) * 40 + cl] = f2bf(v.w);
        }
        short8 a = *(const short8*)(Wpb + (size_t)(o0 + l16) * 256 + k0 + oct * 8);
        __syncthreads();
        #pragma unroll
        for (int f = 0; f < 4; ++f) {
            short8 b = *(const short8*)&Bt[(f * 16 + l16) * 40 + oct * 8];
            acc[f] = __builtin_amdgcn_mfma_f32_16x16x32_bf16(a, b, acc[f], 0, 0, 0);
        }
    }

    #pragma unroll
    for (int f = 0; f < 4; ++f) {
        int p = p0 + f * 16 + l16;
        #pragma unroll
        for (int r = 0; r < 4; ++r) {
            int o = o0 + oct * 4 + r;
            proj[((size_t)(n * 256 + o)) * NPOS + p] = acc[f][r] + bpv[o];
        }
    }
}

// ---------------------------------------------------------------------------
// Kernel 6: bilinear 48->96 upsample + residual
// ---------------------------------------------------------------------------
__global__ __launch_bounds__(256) void resize_kernel(
    const float* __restrict__ proj, const float* __restrict__ x,
    const float* __restrict__ gamma, float* __restrict__ out)
{
    int idx = blockIdx.x * 256 + threadIdx.x;
    int J = idx % 96;
    int tmp = idx / 96;
    int I = tmp % 96;
    int nc = tmp / 96;

    int jr = I >> 1;
    int r0, r1; float w0, w1;
    if ((I & 1) == 0) { r0 = (jr > 0) ? jr - 1 : 0; r1 = jr; w0 = 0.25f; w1 = 0.75f; }
    else              { r0 = jr; r1 = (jr < 47) ? jr + 1 : 47; w0 = 0.75f; w1 = 0.25f; }
    int jc = J >> 1;
    int c0, c1; float u0, u1;
    if ((J & 1) == 0) { c0 = (jc > 0) ? jc - 1 : 0; c1 = jc; u0 = 0.25f; u1 = 0.75f; }
    else              { c0 = jc; c1 = (jc < 47) ? jc + 1 : 47; u0 = 0.75f; u1 = 0.25f; }

    const float* P = proj + (size_t)nc * NPOS;
    float v = w0 * (u0 * P[r0 * 48 + c0] + u1 * P[r0 * 48 + c1]) +
              w1 * (u0 * P[r1 * 48 + c0] + u1 * P[r1 * 48 + c1]);
    out[idx] = gamma[0] * v + x[idx];
}

// ---------------------------------------------------------------------------
extern "C" void kernel_launch(void* const* d_in, const int* in_sizes, int n_in,
                              void* d_out, int out_size, void* d_ws, size_t ws_size,
                              hipStream_t stream)
{
    const float* x     = (const float*)d_in[0];
    const float* Wq    = (const float*)d_in[1];
    const float* Wk    = (const float*)d_in[2];
    const float* Wv    = (const float*)d_in[3];
    const float* Wx    = (const float*)d_in[4];
    const float* Wy    = (const float*)d_in[5];
    const float* ab    = (const float*)d_in[6];
    const float* Wp    = (const float*)d_in[7];
    const float* bp    = (const float*)d_in[8];
    const float* gamma = (const float*)d_in[9];
    float* out = (float*)d_out;

    unsigned short* posxb = (unsigned short*)d_ws;        // 8*96*32 bf16
    unsigned short* posyb = posxb + 8 * 96 * 32;          // 8*96*32 bf16
    float* wkeff = (float*)(posyb + 8 * 96 * 32);         // 8*256 fp32
    unsigned short* Wb  = (unsigned short*)(wkeff + 8 * 256);   // 576*256 bf16
    unsigned short* Wpb = Wb + (size_t)576 * 256;               // 256*256 bf16
    unsigned short* qbuf = Wpb + (size_t)256 * 256;             // 2*8*2304*32 bf16
    float* vbuf  = (float*)(qbuf + (size_t)2 * 8 * NPOS * 32);  // fp32
    float* ekA   = vbuf + (size_t)2 * 8 * NPOS * 32;
    float* oattn = ekA + 2 * 8 * NPOS;
    float* proj  = oattn + (size_t)2 * 256 * NPOS;
    // Aliases (stream-ordered lifetimes):
    float* xs    = oattn;          // extract output, dead after qkv
    uint4* vhat  = (uint4*)proj;   // dead after attn

    hipLaunchKernelGGL(pos_tables_kernel, dim3(104), dim3(256), 0, stream,
                       Wx, Wy, Wk, ab, posxb, posyb, wkeff);
    hipLaunchKernelGGL(extract_kernel, dim3(1152), dim3(256), 0, stream, x, xs);
    hipLaunchKernelGGL(wconv_kernel, dim3(832), dim3(256), 0, stream,
                       Wq, Wv, wkeff, Wp, Wb, Wpb);
    hipLaunchKernelGGL(qkv_kernel, dim3(9, 72), dim3(256), 0, stream,
                       xs, Wb, qbuf, vbuf, ekA);
    hipLaunchKernelGGL(softA_kernel, dim3(16), dim3(256), 0, stream, ekA);
    hipLaunchKernelGGL(vhat_kernel, dim3(24, 16), dim3(256), 0, stream,
                       vbuf, ekA, vhat);
    hipLaunchKernelGGL(attn_kernel, dim3(576), dim3(256), 0, stream,
                       qbuf, posxb, posyb, vhat, oattn);
    hipLaunchKernelGGL(proj_kernel, dim3(4, 72), dim3(256), 0, stream,
                       oattn, Wpb, bp, proj);
    hipLaunchKernelGGL(resize_kernel, dim3((2 * 256 * 96 * 96) / 256), dim3(256), 0, stream,
                       proj, x, gamma, out);
}

// Round 10
// 168.589 us; speedup vs baseline: 1.4735x; 1.0158x over previous
//
#include <hip/hip_runtime.h>
#include <hip/hip_bf16.h>
#include <math.h>

// Problem constants
#define NB 2
#define CC 256
#define NPOS 2304   // 48*48
#define NDELTA 95

typedef __attribute__((ext_vector_type(8))) short short8;
typedef __attribute__((ext_vector_type(4))) float floatx4;

__device__ inline unsigned short f2bf(float x) {
    unsigned int u = __float_as_uint(x);
    u = (u + 0x7FFFu + ((u >> 16) & 1u)) >> 16;
    return (unsigned short)u;
}
__device__ inline float bf2f(unsigned short h) {
    return __uint_as_float(((unsigned int)h) << 16);
}
__device__ inline unsigned int pk2(float a, float b) {
    return (unsigned int)f2bf(a) | ((unsigned int)f2bf(b) << 16);
}
__device__ inline unsigned int pkmul(unsigned int a, unsigned int b) {
    __hip_bfloat162 x = *(__hip_bfloat162*)&a;
    __hip_bfloat162 y = *(__hip_bfloat162*)&b;
    __hip_bfloat162 r = __hmul2(x, y);
    return *(unsigned int*)&r;
}

// ---------------------------------------------------------------------------
// Kernel 1: fused prep. Grid 992:
//   b<95: pos δ row -> posxb/posyb[8 g][96 δ][32 d] bf16
//   b==95: zero δ=95 pad row
//   b<736: Wb row o=b-96 (Wq | Wv | wkeff-inline | zero pad to 640)
//   else:  Wpb row o=b-736
// ---------------------------------------------------------------------------
__global__ __launch_bounds__(256) void prep_kernel(
    const float* __restrict__ Wx, const float* __restrict__ Wy,
    const float* __restrict__ Wk, const float* __restrict__ ab,
    const float* __restrict__ Wq, const float* __restrict__ Wv,
    const float* __restrict__ Wp,
    unsigned short* __restrict__ posxb, unsigned short* __restrict__ posyb,
    unsigned short* __restrict__ Wb, unsigned short* __restrict__ Wpb)
{
    int b = blockIdx.x;
    int t = threadIdx.x;
    if (b < NDELTA) {
        __shared__ float emb[128];
        float delta = (float)(b - 47);
        if (t < 64) {
            float dim_inv = exp2f(-(float)t * 0.15571537944784511f); // log2(1000)/64
            float ang = 2.0f * delta * dim_inv;
            emb[t]      = sinf(ang);
            emb[t + 64] = cosf(ang);
        }
        __syncthreads();
        float sx = 0.f, sy = 0.f;
        const float* wxr = Wx + t * 128;
        const float* wyr = Wy + t * 128;
        for (int f = 0; f < 128; ++f) {
            float e = emb[f];
            sx += e * wxr[f];
            sy += e * wyr[f];
        }
        const float inv_sqrt2 = 0.70710678118654752440f;
        int g = t >> 5, d = t & 31;
        posxb[((size_t)g * 96 + b) * 32 + d] = f2bf(sx * inv_sqrt2);
        posyb[((size_t)g * 96 + b) * 32 + d] = f2bf(sy * inv_sqrt2);
    } else if (b == NDELTA) {
        int g = t >> 5, d = t & 31;
        posxb[((size_t)g * 96 + 95) * 32 + d] = 0;
        posyb[((size_t)g * 96 + 95) * 32 + d] = 0;
    } else if (b < 96 + 640) {
        int o = b - 96;
        float v = 0.f;
        if (o < 256)      v = Wq[o * 256 + t];
        else if (o < 512) v = Wv[(o - 256) * 256 + t];
        else if (o < 520) {
            int g = o - 512;
            float s = 0.f;
            for (int d = 0; d < 32; ++d)
                s += ab[g * 32 + d] * Wk[(g * 32 + d) * 256 + t];
            v = s;
        }
        Wb[(size_t)o * 256 + t] = f2bf(v);
    } else {
        int o = b - 736;
        Wpb[(size_t)o * 256 + t] = f2bf(Wp[o * 256 + t]);
    }
}

// ---------------------------------------------------------------------------
// Kernel 2: extract x[:, :, ::2, ::2] -> bf16 TRANSPOSED xs_t[n][p][256 c].
// Grid (2 n x 36 ptile). LDS transpose, pad 264 (16B-aligned rows, 2-way banks).
// ---------------------------------------------------------------------------
__global__ __launch_bounds__(256) void extract_kernel(
    const float* __restrict__ x, unsigned short* __restrict__ xs_t)
{
    __shared__ __align__(16) unsigned short Lt[64][264];
    int blk = blockIdx.x;
    int pt = blk % 36;
    int n = blk / 36;
    int p0 = pt * 64;
    int t = threadIdx.x;
    int cw = t >> 4;      // 0..15
    int pl = t & 15;

    for (int cc = 0; cc < 16; ++cc) {
        int c = cc * 16 + cw;
        const float* src = x + ((size_t)(n * 256 + c)) * (96 * 96);
        #pragma unroll
        for (int k = 0; k < 4; ++k) {
            int p = p0 + pl + k * 16;
            int i = p / 48, j = p - i * 48;
            Lt[pl + k * 16][c] = f2bf(src[(2 * i) * 96 + 2 * j]);
        }
    }
    __syncthreads();
    #pragma unroll
    for (int it = 0; it < 8; ++it) {
        int s = t + it * 256;
        int p = s >> 5, c8 = s & 31;
        uint4 v = *(const uint4*)&Lt[p][c8 * 8];
        *(uint4*)(xs_t + ((size_t)(n * NPOS + p0 + p)) * 256 + c8 * 8) = v;
    }
}

// ---------------------------------------------------------------------------
// Kernel 3: Q/V/e_key projection — pure-MFMA, no LDS, no barriers.
// Wave = M32 x N64, block = 4 waves stacked in m (M128). Grid (5, 72).
// A: Wb[o][k] bf16 direct 16B loads. B: xs_t[p][k] bf16 direct 16B loads.
// ---------------------------------------------------------------------------
__global__ __launch_bounds__(256, 2) void qkv_kernel(
    const unsigned short* __restrict__ xs_t, const unsigned short* __restrict__ Wb,
    unsigned short* __restrict__ qbuf, float* __restrict__ vbuf,
    float* __restrict__ ek)
{
    int mT = blockIdx.x;           // 0..4
    int nT = blockIdx.y;           // 0..71
    int t = threadIdx.x;
    int wm = t >> 6, L = t & 63, l16 = L & 15, oct = L >> 4;
    int colBase = nT * 64;
    int n = colBase / NPOS;
    int p0 = colBase - n * NPOS;
    int o_w = mT * 128 + wm * 32;

    const unsigned short* A0 = Wb + (size_t)(o_w + l16) * 256 + oct * 8;
    const unsigned short* A1 = A0 + 16 * 256;
    const unsigned short* B0 = xs_t + ((size_t)(n * NPOS + p0 + l16)) * 256 + oct * 8;

    floatx4 acc[2][4] = {};
    #pragma unroll
    for (int kc = 0; kc < 8; ++kc) {
        int k0 = kc * 32;
        short8 a0 = *(const short8*)(A0 + k0);
        short8 a1 = *(const short8*)(A1 + k0);
        short8 b0 = *(const short8*)(B0 + k0);
        short8 b1 = *(const short8*)(B0 + 16 * 256 + k0);
        short8 b2 = *(const short8*)(B0 + 32 * 256 + k0);
        short8 b3 = *(const short8*)(B0 + 48 * 256 + k0);
        acc[0][0] = __builtin_amdgcn_mfma_f32_16x16x32_bf16(a0, b0, acc[0][0], 0, 0, 0);
        acc[0][1] = __builtin_amdgcn_mfma_f32_16x16x32_bf16(a0, b1, acc[0][1], 0, 0, 0);
        acc[0][2] = __builtin_amdgcn_mfma_f32_16x16x32_bf16(a0, b2, acc[0][2], 0, 0, 0);
        acc[0][3] = __builtin_amdgcn_mfma_f32_16x16x32_bf16(a0, b3, acc[0][3], 0, 0, 0);
        acc[1][0] = __builtin_amdgcn_mfma_f32_16x16x32_bf16(a1, b0, acc[1][0], 0, 0, 0);
        acc[1][1] = __builtin_amdgcn_mfma_f32_16x16x32_bf16(a1, b1, acc[1][1], 0, 0, 0);
        acc[1][2] = __builtin_amdgcn_mfma_f32_16x16x32_bf16(a1, b2, acc[1][2], 0, 0, 0);
        acc[1][3] = __builtin_amdgcn_mfma_f32_16x16x32_bf16(a1, b3, acc[1][3], 0, 0, 0);
    }

    #pragma unroll
    for (int af = 0; af < 2; ++af) {
        #pragma unroll
        for (int f = 0; f < 4; ++f) {
            int p = p0 + f * 16 + l16;
            #pragma unroll
            for (int r = 0; r < 4; ++r) {
                int o = o_w + af * 16 + oct * 4 + r;
                float val = acc[af][f][r];
                if (o < 256) {
                    int g = o >> 5, d = o & 31;
                    qbuf[((size_t)(n * 8 + g) * NPOS + p) * 32 + d] = f2bf(val);
                } else if (o < 512) {
                    vbuf[((size_t)(n * 256 + (o - 256))) * NPOS + p] = val;
                } else if (o < 520) {
                    ek[((size_t)(n * 8 + (o - 512))) * NPOS + p] = val;
                }
            }
        }
    }
}

// ---------------------------------------------------------------------------
// Kernel 4: per-(n,g) A = exp(ek - max(ek)), in place.
// ---------------------------------------------------------------------------
__global__ __launch_bounds__(256) void softA_kernel(float* __restrict__ ekA)
{
    int ng = blockIdx.x;
    float* e = ekA + (size_t)ng * NPOS;
    int t = threadIdx.x;
    __shared__ float red[256];
    float m = -1e30f;
    for (int k = t; k < NPOS; k += 256) m = fmaxf(m, e[k]);
    red[t] = m;
    __syncthreads();
    for (int s = 128; s > 0; s >>= 1) {
        if (t < s) red[t] = fmaxf(red[t], red[t + s]);
        __syncthreads();
    }
    m = red[0];
    for (int k = t; k < NPOS; k += 256) e[k] = __expf(e[k] - m);
}

// ---------------------------------------------------------------------------
// Kernel 5: V̂ = A*V in bf16 B-fragment order, once per (n,g).
// ---------------------------------------------------------------------------
__global__ __launch_bounds__(256) void vhat_kernel(
    const float* __restrict__ vbuf, const float* __restrict__ ekA,
    uint4* __restrict__ vhat)
{
    int tile = blockIdx.x;   // 0..23
    int ng = blockIdx.y;     // 0..15
    int k0 = tile * 96;
    int t = threadIdx.x;
    const float* vb = vbuf + (size_t)ng * 32 * NPOS;
    const float* Ab = ekA + (size_t)ng * NPOS;
    uint4* out = vhat + ((size_t)ng * 24 + tile) * 576;

    for (int s = t; s < 576; s += 256) {
        int grp = s >> 6;
        int Ls = s & 63;
        int cc = grp / 3;
        int nn = grp - cc * 3;
        int koct = cc * 32 + ((Ls >> 4) << 3);
        uint4 w = make_uint4(0u, 0u, 0u, 0u);
        if (nn < 2) {
            int d = nn * 16 + (Ls & 15);
            const float* vp = vb + (size_t)d * NPOS + k0 + koct;
            const float* ap = Ab + k0 + koct;
            float4 v0 = *(const float4*)vp;
            float4 v1 = *(const float4*)(vp + 4);
            float4 a0 = *(const float4*)ap;
            float4 a1 = *(const float4*)(ap + 4);
            w.x = pk2(v0.x * a0.x, v0.y * a0.y);
            w.y = pk2(v0.z * a0.z, v0.w * a0.w);
            w.z = pk2(v1.x * a1.x, v1.y * a1.y);
            w.w = pk2(v1.z * a1.z, v1.w * a1.w);
        } else if ((Ls & 15) == 0) {
            const float* ap = Ab + k0 + koct;
            float4 a0 = *(const float4*)ap;
            float4 a1 = *(const float4*)(ap + 4);
            w.x = pk2(a0.x, a0.y);
            w.y = pk2(a0.z, a0.w);
            w.z = pk2(a1.x, a1.y);
            w.w = pk2(a1.z, a1.w);
        }
        out[s] = w;
    }
}

// ---------------------------------------------------------------------------
// Kernel 6: attention (r8 structure; epilogue -> bf16 transposed oattn_t).
// ---------------------------------------------------------------------------
#define DO_TILE(BB, TT) do {                                                   \
    int u0_ = (TT) * 2;                                                        \
    unsigned int y0_ = Ys[qp * 50 + u0_];     y0_ |= y0_ << 16;                \
    unsigned int y1_ = Ys[qp * 50 + u0_ + 1]; y1_ |= y1_ << 16;                \
    unsigned int Yc0_ = y0_, Yc1_ = (o < 2) ? y0_ : y1_, Yc2_ = y1_;           \
    union { unsigned int u[4]; short8 s; } av_;                                \
    av_.u[0] = pkmul(Xp[0], Yc0_); av_.u[1] = pkmul(Xp[1], Yc0_);              \
    av_.u[2] = pkmul(Xp[2], Yc0_); av_.u[3] = pkmul(Xp[3], Yc0_);              \
    acc0 = __builtin_amdgcn_mfma_f32_16x16x32_bf16(av_.s, *(const short8*)&BB[0], acc0, 0, 0, 0); \
    acc1 = __builtin_amdgcn_mfma_f32_16x16x32_bf16(av_.s, *(const short8*)&BB[1], acc1, 0, 0, 0); \
    acc2 = __builtin_amdgcn_mfma_f32_16x16x32_bf16(av_.s, *(const short8*)&BB[2], acc2, 0, 0, 0); \
    av_.u[0] = pkmul(Xp[4], Yc1_); av_.u[1] = pkmul(Xp[5], Yc1_);              \
    av_.u[2] = pkmul(Xp[6], Yc1_); av_.u[3] = pkmul(Xp[7], Yc1_);              \
    acc0 = __builtin_amdgcn_mfma_f32_16x16x32_bf16(av_.s, *(const short8*)&BB[3], acc0, 0, 0, 0); \
    acc1 = __builtin_amdgcn_mfma_f32_16x16x32_bf16(av_.s, *(const short8*)&BB[4], acc1, 0, 0, 0); \
    acc2 = __builtin_amdgcn_mfma_f32_16x16x32_bf16(av_.s, *(const short8*)&BB[5], acc2, 0, 0, 0); \
    av_.u[0] = pkmul(Xp[8], Yc2_); av_.u[1] = pkmul(Xp[9], Yc2_);              \
    av_.u[2] = pkmul(Xp[10], Yc2_); av_.u[3] = pkmul(Xp[11], Yc2_);            \
    acc0 = __builtin_amdgcn_mfma_f32_16x16x32_bf16(av_.s, *(const short8*)&BB[6], acc0, 0, 0, 0); \
    acc1 = __builtin_amdgcn_mfma_f32_16x16x32_bf16(av_.s, *(const short8*)&BB[7], acc1, 0, 0, 0); \
    acc2 = __builtin_amdgcn_mfma_f32_16x16x32_bf16(av_.s, *(const short8*)&BB[8], acc2, 0, 0, 0); \
} while (0)

__global__ __launch_bounds__(256, 2) void attn_kernel(
    const unsigned short* __restrict__ qbuf, const unsigned short* __restrict__ posxb,
    const unsigned short* __restrict__ posyb, const uint4* __restrict__ vhat,
    unsigned short* __restrict__ oattn_t)
{
    __shared__ unsigned short Xs[64 * 50];
    __shared__ unsigned short Ys[64 * 50];
    __shared__ float linv_s[64];

    int blk = blockIdx.x;
    int qt = blk % 36;
    int ng = blk / 36;
    int nb = ng >> 3, g = ng & 7;
    int qbase = qt * 64;
    int t = threadIdx.x;
    int m = t >> 6, L = t & 63;
    int l16 = L & 15, oct = L >> 4;

    // ---- prologue: T = Q·pos^T via MFMA, X/Y = exp(T) into LDS ----
    {
        int qtile0 = qbase + m * 16;
        int hq = qtile0 / 48;
        int wq0 = qtile0 - hq * 48;
        short8 aq = *(const short8*)(qbuf +
            ((size_t)ng * NPOS + qtile0 + l16) * 32 + oct * 8);
        const unsigned short* pxg = posxb + (size_t)g * 96 * 32;
        const unsigned short* pyg = posyb + (size_t)g * 96 * 32;
        floatx4 zero = {0.f, 0.f, 0.f, 0.f};
        #pragma unroll
        for (int j = 0; j < 6; ++j) {
            int dl = j * 16 + l16;
            short8 bx = *(const short8*)(pxg + (size_t)dl * 32 + oct * 8);
            short8 by = *(const short8*)(pyg + (size_t)dl * 32 + oct * 8);
            floatx4 tx = __builtin_amdgcn_mfma_f32_16x16x32_bf16(aq, bx, zero, 0, 0, 0);
            floatx4 ty = __builtin_amdgcn_mfma_f32_16x16x32_bf16(aq, by, zero, 0, 0, 0);
            int u = hq + 47 - dl;
            bool uok = (u >= 0) && (u < 48);
            #pragma unroll
            for (int r = 0; r < 4; ++r) {
                int ql = oct * 4 + r;
                int v = wq0 + ql + 47 - dl;
                if (v >= 0 && v < 48)
                    Xs[(m * 16 + ql) * 50 + v] = f2bf(__expf(tx[r]));
                if (uok)
                    Ys[(m * 16 + ql) * 50 + u] = f2bf(__expf(ty[r]));
            }
        }
    }
    __syncthreads();

    int qp = m * 16 + l16;
    int o = oct;
    unsigned int Xp[12];
    #pragma unroll
    for (int c = 0; c < 3; ++c)
        #pragma unroll
        for (int jj = 0; jj < 4; ++jj) {
            int k = c * 32 + o * 8 + jj * 2;
            int v0 = (k < 48) ? k : k - 48;
            Xp[c * 4 + jj] = *(const unsigned int*)&Xs[qp * 50 + v0];
        }

    floatx4 acc0 = {0.f, 0.f, 0.f, 0.f};
    floatx4 acc1 = {0.f, 0.f, 0.f, 0.f};
    floatx4 acc2 = {0.f, 0.f, 0.f, 0.f};

    const uint4* vb = vhat + (size_t)ng * 24 * 576 + L;
    uint4 Abuf[9], Bbuf[9];
    #pragma unroll
    for (int gg = 0; gg < 9; ++gg) Abuf[gg] = vb[gg * 64];

    for (int tile = 0; tile < 24; tile += 2) {
        const uint4* sB = vb + (tile + 1) * 576;
        #pragma unroll
        for (int gg = 0; gg < 9; ++gg) Bbuf[gg] = sB[gg * 64];
        DO_TILE(Abuf, tile);
        if (tile + 2 < 24) {
            const uint4* sA = vb + (tile + 2) * 576;
            #pragma unroll
            for (int gg = 0; gg < 9; ++gg) Abuf[gg] = sA[gg * 64];
        }
        DO_TILE(Bbuf, tile + 1);
    }

    if ((L & 15) == 0) {
        int qc = m * 16 + (L >> 4) * 4;
        #pragma unroll
        for (int r = 0; r < 4; ++r)
            linv_s[qc + r] = 1.0f / acc2[r];
    }
    __syncthreads();
    {
        int qc = m * 16 + (L >> 4) * 4;
        int d0 = L & 15;
        #pragma unroll
        for (int r = 0; r < 4; ++r) {
            float lir = linv_s[qc + r];
            size_t row = ((size_t)nb * NPOS + qbase + qc + r) * 256;
            oattn_t[row + g * 32 + d0]      = f2bf(acc0[r] * lir);
            oattn_t[row + g * 32 + 16 + d0] = f2bf(acc1[r] * lir);
        }
    }
}

// ---------------------------------------------------------------------------
// Kernel 7: output projection — pure-MFMA, no LDS/barriers (qkv structure).
// Grid (2, 72). Output projb bf16 [n][256 o][p] + bias.
// ---------------------------------------------------------------------------
__global__ __launch_bounds__(256, 2) void proj_kernel(
    const unsigned short* __restrict__ oattn_t, const unsigned short* __restrict__ Wpb,
    const float* __restrict__ bpv, unsigned short* __restrict__ projb)
{
    int mT = blockIdx.x;           // 0..1
    int nT = blockIdx.y;           // 0..71
    int t = threadIdx.x;
    int wm = t >> 6, L = t & 63, l16 = L & 15, oct = L >> 4;
    int colBase = nT * 64;
    int n = colBase / NPOS;
    int p0 = colBase - n * NPOS;
    int o_w = mT * 128 + wm * 32;

    const unsigned short* A0 = Wpb + (size_t)(o_w + l16) * 256 + oct * 8;
    const unsigned short* A1 = A0 + 16 * 256;
    const unsigned short* B0 = oattn_t + ((size_t)(n * NPOS + p0 + l16)) * 256 + oct * 8;

    floatx4 acc[2][4] = {};
    #pragma unroll
    for (int kc = 0; kc < 8; ++kc) {
        int k0 = kc * 32;
        short8 a0 = *(const short8*)(A0 + k0);
        short8 a1 = *(const short8*)(A1 + k0);
        short8 b0 = *(const short8*)(B0 + k0);
        short8 b1 = *(const short8*)(B0 + 16 * 256 + k0);
        short8 b2 = *(const short8*)(B0 + 32 * 256 + k0);
        short8 b3 = *(const short8*)(B0 + 48 * 256 + k0);
        acc[0][0] = __builtin_amdgcn_mfma_f32_16x16x32_bf16(a0, b0, acc[0][0], 0, 0, 0);
        acc[0][1] = __builtin_amdgcn_mfma_f32_16x16x32_bf16(a0, b1, acc[0][1], 0, 0, 0);
        acc[0][2] = __builtin_amdgcn_mfma_f32_16x16x32_bf16(a0, b2, acc[0][2], 0, 0, 0);
        acc[0][3] = __builtin_amdgcn_mfma_f32_16x16x32_bf16(a0, b3, acc[0][3], 0, 0, 0);
        acc[1][0] = __builtin_amdgcn_mfma_f32_16x16x32_bf16(a1, b0, acc[1][0], 0, 0, 0);
        acc[1][1] = __builtin_amdgcn_mfma_f32_16x16x32_bf16(a1, b1, acc[1][1], 0, 0, 0);
        acc[1][2] = __builtin_amdgcn_mfma_f32_16x16x32_bf16(a1, b2, acc[1][2], 0, 0, 0);
        acc[1][3] = __builtin_amdgcn_mfma_f32_16x16x32_bf16(a1, b3, acc[1][3], 0, 0, 0);
    }

    #pragma unroll
    for (int af = 0; af < 2; ++af) {
        #pragma unroll
        for (int f = 0; f < 4; ++f) {
            int p = p0 + f * 16 + l16;
            #pragma unroll
            for (int r = 0; r < 4; ++r) {
                int o = o_w + af * 16 + oct * 4 + r;
                projb[((size_t)(n * 256 + o)) * NPOS + p] = f2bf(acc[af][f][r] + bpv[o]);
            }
        }
    }
}

// ---------------------------------------------------------------------------
// Kernel 8: bilinear 48->96 upsample (bf16 proj) + residual
// ---------------------------------------------------------------------------
__global__ __launch_bounds__(256) void resize_kernel(
    const unsigned short* __restrict__ projb, const float* __restrict__ x,
    const float* __restrict__ gamma, float* __restrict__ out)
{
    int idx = blockIdx.x * 256 + threadIdx.x;
    int J = idx % 96;
    int tmp = idx / 96;
    int I = tmp % 96;
    int nc = tmp / 96;

    int jr = I >> 1;
    int r0, r1; float w0, w1;
    if ((I & 1) == 0) { r0 = (jr > 0) ? jr - 1 : 0; r1 = jr; w0 = 0.25f; w1 = 0.75f; }
    else              { r0 = jr; r1 = (jr < 47) ? jr + 1 : 47; w0 = 0.75f; w1 = 0.25f; }
    int jc = J >> 1;
    int c0, c1; float u0, u1;
    if ((J & 1) == 0) { c0 = (jc > 0) ? jc - 1 : 0; c1 = jc; u0 = 0.25f; u1 = 0.75f; }
    else              { c0 = jc; c1 = (jc < 47) ? jc + 1 : 47; u0 = 0.75f; u1 = 0.25f; }

    const unsigned short* P = projb + (size_t)nc * NPOS;
    float v = w0 * (u0 * bf2f(P[r0 * 48 + c0]) + u1 * bf2f(P[r0 * 48 + c1])) +
              w1 * (u0 * bf2f(P[r1 * 48 + c0]) + u1 * bf2f(P[r1 * 48 + c1]));
    out[idx] = gamma[0] * v + x[idx];
}

// ---------------------------------------------------------------------------
extern "C" void kernel_launch(void* const* d_in, const int* in_sizes, int n_in,
                              void* d_out, int out_size, void* d_ws, size_t ws_size,
                              hipStream_t stream)
{
    const float* x     = (const float*)d_in[0];
    const float* Wq    = (const float*)d_in[1];
    const float* Wk    = (const float*)d_in[2];
    const float* Wv    = (const float*)d_in[3];
    const float* Wx    = (const float*)d_in[4];
    const float* Wy    = (const float*)d_in[5];
    const float* ab    = (const float*)d_in[6];
    const float* Wp    = (const float*)d_in[7];
    const float* bp    = (const float*)d_in[8];
    const float* gamma = (const float*)d_in[9];
    float* out = (float*)d_out;

    unsigned short* posxb = (unsigned short*)d_ws;           // 8*96*32
    unsigned short* posyb  = posxb + 8 * 96 * 32;
    unsigned short* Wb     = posyb + 8 * 96 * 32;            // 640*256
    unsigned short* Wpb    = Wb + (size_t)640 * 256;         // 256*256
    unsigned short* xs_t   = Wpb + (size_t)256 * 256;        // 2*2304*256
    unsigned short* qbuf   = xs_t + (size_t)2 * NPOS * 256;  // 2*8*2304*32
    unsigned short* oattn_t= qbuf + (size_t)2 * NPOS * 256;  // 2*2304*256
    unsigned short* projb  = oattn_t + (size_t)2 * NPOS * 256; // 2*256*2304
    float* vbuf  = (float*)(projb + (size_t)2 * NPOS * 256); // 2*256*2304 fp32
    float* ekA   = vbuf + (size_t)2 * 256 * NPOS;            // 16*2304
    uint4* vhat  = (uint4*)(ekA + 16 * NPOS);                // 16*24*576 uint4

    hipLaunchKernelGGL(prep_kernel, dim3(992), dim3(256), 0, stream,
                       Wx, Wy, Wk, ab, Wq, Wv, Wp, posxb, posyb, Wb, Wpb);
    hipLaunchKernelGGL(extract_kernel, dim3(72), dim3(256), 0, stream, x, xs_t);
    hipLaunchKernelGGL(qkv_kernel, dim3(5, 72), dim3(256), 0, stream,
                       xs_t, Wb, qbuf, vbuf, ekA);
    hipLaunchKernelGGL(softA_kernel, dim3(16), dim3(256), 0, stream, ekA);
    hipLaunchKernelGGL(vhat_kernel, dim3(24, 16), dim3(256), 0, stream,
                       vbuf, ekA, vhat);
    hipLaunchKernelGGL(attn_kernel, dim3(576), dim3(256), 0, stream,
                       qbuf, posxb, posyb, vhat, oattn_t);
    hipLaunchKernelGGL(proj_kernel, dim3(2, 72), dim3(256), 0, stream,
                       oattn_t, Wpb, bp, projb);
    hipLaunchKernelGGL(resize_kernel, dim3((2 * 256 * 96 * 96) / 256), dim3(256), 0, stream,
                       projb, x, gamma, out);
}